// Round 7
// baseline (209.707 us; speedup 1.0000x reference)
//
#include <hip/hip_runtime.h>
#include <hip/hip_bf16.h>
#include <math.h>

#define NNODE 3000
#define NCHUNK 47  // ceil(3000/64)
#define ALPHA 0.2f
#define LDT 3008   // padded m-stride of WhT (bf16)
#define LOG2E 1.4426950408889634f

typedef __attribute__((ext_vector_type(8))) short short8v;
typedef __attribute__((ext_vector_type(4))) short short4v;
typedef __attribute__((ext_vector_type(4))) float float4v;

static __device__ __forceinline__ short f2b(float x) {
  __hip_bfloat16 b = __float2bfloat16(x);
  return *reinterpret_cast<short*>(&b);
}

// ---------------- adj -> bitmask ----------------
__global__ __launch_bounds__(256)
void k_bitmask(const int* __restrict__ adj, unsigned long long* __restrict__ bm) {
  int row = blockIdx.x * 4 + (threadIdx.x >> 6);
  int lane = threadIdx.x & 63;
  if (row >= 2 * NNODE) return;
  const int* arow = adj + (size_t)row * NNODE;
  unsigned long long* brow = bm + (size_t)row * NCHUNK;
  for (int c = 0; c < NCHUNK; ++c) {
    int m = c * 64 + lane;
    int v = (m < NNODE) ? (arow[m] > 0) : 0;
    unsigned long long mask = __ballot(v);
    if (lane == 0) brow[c] = mask;
  }
}

// ---------------- fp32 -> bf16 cast (8 elems/thread) ----------------
__global__ __launch_bounds__(256)
void k_cast(const float* __restrict__ src, unsigned short* __restrict__ dst,
            int count8) {
  int i = blockIdx.x * 256 + threadIdx.x;
  if (i >= count8) return;
  float4 va = reinterpret_cast<const float4*>(src)[2 * i];
  float4 vb = reinterpret_cast<const float4*>(src)[2 * i + 1];
  short8v w;
  w[0] = f2b(va.x); w[1] = f2b(va.y); w[2] = f2b(va.z); w[3] = f2b(va.w);
  w[4] = f2b(vb.x); w[5] = f2b(vb.y); w[6] = f2b(vb.z); w[7] = f2b(vb.w);
  reinterpret_cast<short8v*>(dst)[i] = w;
}

// ------- weight transpose+cast: src [z][rows][O] f32 -> dst [z][O][ldT] bf16 -------
template <int O>
__global__ __launch_bounds__(256)
void k_wt(const float* __restrict__ src, unsigned short* __restrict__ dst,
          int rows, int ldT) {
  const int z = blockIdx.y;
  const int m0 = blockIdx.x * 64;
  src += (size_t)z * rows * O;
  dst += (size_t)z * O * ldT;
  __shared__ float Lw[64][O + 4];
  const int tid = threadIdx.x;
  for (int idx = tid; idx < 64 * (O / 4); idx += 256) {
    int m = idx / (O / 4), oc = idx % (O / 4);
    float4 v = make_float4(0.f, 0.f, 0.f, 0.f);
    if (m0 + m < rows)
      v = *reinterpret_cast<const float4*>(&src[(size_t)(m0 + m) * O + 4 * oc]);
    *reinterpret_cast<float4*>(&Lw[m][4 * oc]) = v;
  }
  __syncthreads();
  const int o = tid & (O - 1);
  for (int mc = tid / O; mc < 8; mc += 256 / O) {
    short8v w;
#pragma unroll
    for (int j = 0; j < 8; ++j) w[j] = f2b(Lw[8 * mc + j][o]);
    *reinterpret_cast<short8v*>(&dst[(size_t)o * ldT + m0 + 8 * mc]) = w;
  }
}

// ---------------- bf16 MFMA GEMM, 32 rows x OW cols per 128-thr block ----------------
template <int OW, int KC, int MODE, int ACT>
__global__ __launch_bounds__(128)
void k_xw(const unsigned short* __restrict__ Ab, long long boffA,
          const unsigned short* __restrict__ Bb, long long boffB,
          const float* __restrict__ aux,
          unsigned short* __restrict__ Wo,
          long long boffW,
          float* __restrict__ f1o, float* __restrict__ f2o,
          int colStrideZ, int ldC) {
  constexpr int NCT = OW / 16;
  const int z = blockIdx.z;
  const int n0 = blockIdx.x * 32;
  const int ocol0 = blockIdx.y * OW;
  const unsigned short* A = Ab + boffA * z;
  const unsigned short* B = Bb + boffB * z;
  const int tid = threadIdx.x;
  const int l = tid & 63, g = l >> 4, li = l & 15;
  const int r0 = 16 * (tid >> 6);
  __shared__ __align__(16) unsigned short As[32 * 64];
  __shared__ __align__(16) unsigned short Bs[OW * 64];
  float4v acc[NCT];
#pragma unroll
  for (int ct = 0; ct < NCT; ++ct) acc[ct] = {0.f, 0.f, 0.f, 0.f};
  for (int k0 = 0; k0 < KC; k0 += 64) {
    for (int i = tid; i < 256; i += 128) {
      int r = i >> 3, c8 = i & 7;
      uint4 v = {0u, 0u, 0u, 0u};
      if (n0 + r < NNODE)
        v = *reinterpret_cast<const uint4*>(A + (size_t)(n0 + r) * KC + k0 + 8 * c8);
      int boff = (r * 128 + c8 * 16) ^ ((r & 7) << 4);
      *reinterpret_cast<uint4*>(reinterpret_cast<char*>(As) + boff) = v;
    }
    for (int i = tid; i < OW * 8; i += 128) {
      int ro = i >> 3, c8 = i & 7;
      uint4 v = *reinterpret_cast<const uint4*>(B + (size_t)(ocol0 + ro) * KC + k0 + 8 * c8);
      int boff = (ro * 128 + c8 * 16) ^ ((ro & 7) << 4);
      *reinterpret_cast<uint4*>(reinterpret_cast<char*>(Bs) + boff) = v;
    }
    __syncthreads();
#pragma unroll
    for (int q = 0; q < 2; ++q) {
      int aoff = ((r0 + li) * 128 + q * 64 + 16 * g) ^ ((li & 7) << 4);
      short8v afr = *reinterpret_cast<const short8v*>(
          reinterpret_cast<const char*>(As) + aoff);
#pragma unroll
      for (int ct = 0; ct < NCT; ++ct) {
        int orow = ct * 16 + li;
        int boff = (orow * 128 + q * 64 + 16 * g) ^ ((li & 7) << 4);
        short8v bfr = *reinterpret_cast<const short8v*>(
            reinterpret_cast<const char*>(Bs) + boff);
        acc[ct] = __builtin_amdgcn_mfma_f32_16x16x32_bf16(afr, bfr, acc[ct], 0, 0, 0);
      }
    }
    __syncthreads();
  }
  if (MODE == 1) {
    const float* av = aux + (size_t)z * 2 * OW;
    float p1[4] = {0.f, 0.f, 0.f, 0.f}, p2[4] = {0.f, 0.f, 0.f, 0.f};
#pragma unroll
    for (int ct = 0; ct < NCT; ++ct) {
      float a1v = av[ct * 16 + li];
      float a2v = av[OW + ct * 16 + li];
#pragma unroll
      for (int j = 0; j < 4; ++j) {
        p1[j] += acc[ct][j] * a1v;
        p2[j] += acc[ct][j] * a2v;
      }
    }
#pragma unroll
    for (int off = 1; off < 16; off <<= 1) {
#pragma unroll
      for (int j = 0; j < 4; ++j) {
        p1[j] += __shfl_xor(p1[j], off);
        p2[j] += __shfl_xor(p2[j], off);
      }
    }
    unsigned short* WT = Wo + boffW * z;
#pragma unroll
    for (int ct = 0; ct < NCT; ++ct) {
      short4v w;
#pragma unroll
      for (int j = 0; j < 4; ++j) w[j] = f2b(acc[ct][j]);
      *reinterpret_cast<short4v*>(
          &WT[(size_t)(ocol0 + ct * 16 + li) * LDT + n0 + r0 + 4 * g]) = w;
    }
    if (li == 0) {
#pragma unroll
      for (int j = 0; j < 4; ++j) {
        int n = n0 + r0 + 4 * g + j;
        if (n < NNODE) {
          // pre-scaled by log2(e): score pipeline uses exp2 directly
          f1o[(size_t)z * NNODE + n] = p1[j] * LOG2E;
          f2o[(size_t)z * NNODE + n] = p2[j] * LOG2E;
        }
      }
    }
  } else {
#pragma unroll
    for (int ct = 0; ct < NCT; ++ct) {
      float b = aux[ocol0 + ct * 16 + li];
#pragma unroll
      for (int j = 0; j < 4; ++j) {
        int n = n0 + r0 + 4 * g + j;
        if (n < NNODE) {
          float v = acc[ct][j] + b;
          if (ACT == 1) v = v > 0.f ? v : (__expf(v) - 1.f);
          Wo[(size_t)n * ldC + z * colStrideZ + ocol0 + ct * 16 + li] = (unsigned short)f2b(v);
        }
      }
    }
  }
}

// ---------------- MFMA PV with K-split: partial C + partial rowsum ----------------
// 128 thr, 32 rows, full O cols. Per-tile dbuf staging of Wh tile + bitmask + f2.
// Scores: exp2(pre-scaled lrelu), mask folded into exp input. Rowsum via MFMA
// against a register ones-fragment (lands in output col 0 -> lanes li==0).
template <int O, int CPS>
__global__ __launch_bounds__(128)
void k_pvs(const unsigned short* __restrict__ WhT,
           const float* __restrict__ f1, const float* __restrict__ f2,
           const unsigned long long* __restrict__ bm,
           float* __restrict__ Cpart, float* __restrict__ rsum) {
  constexpr int NCT = O / 16;
  const int z = blockIdx.z, a = z >> 2;
  const int ks = blockIdx.y;
  const int n0 = blockIdx.x * 32;
  const int kc0 = ks * CPS;
  const int nch = (NCHUNK - kc0 < CPS) ? (NCHUNK - kc0) : CPS;
  const int tid = threadIdx.x;
  const int l = tid & 63, li = l & 15, g = l >> 4;
  const int r0 = 16 * (tid >> 6);  // 0 or 16 (2 waves)
  const unsigned short* WT = WhT + (size_t)z * O * LDT;
  const float* f2B = f2 + (size_t)z * NNODE;
  const unsigned long long* bmA = bm + (size_t)a * NNODE * NCHUNK;
  __shared__ __align__(16) unsigned short Whs[2][O * 64];
  __shared__ __align__(16) float F2d[2][64];
  __shared__ unsigned long long Bw2[2][32];
  __shared__ float F1s[32];
  if (tid < 32) {
    int n = n0 + tid;
    F1s[tid] = (n < NNODE) ? f1[(size_t)z * NNODE + n] : 0.f;
  }
  // register ones-fragment: bf16 1.0 in output col 0 (lanes li==0)
  short8v onesf;
  {
    short ov = (li == 0) ? (short)0x3F80 : (short)0;
#pragma unroll
    for (int e = 0; e < 8; ++e) onesf[e] = ov;
  }
  auto stage = [&](int t, int buf) {
    if (tid < 32) {
      int n = n0 + tid;
      Bw2[buf][tid] = (n < NNODE) ? bmA[(size_t)n * NCHUNK + kc0 + t] : 0ULL;
    } else if (tid < 96) {
      int m = (kc0 + t) * 64 + (tid - 32);
      F2d[buf][tid - 32] = (m < NNODE) ? f2B[m] : 0.f;
    }
    for (int i = tid; i < O * 8; i += 128) {
      int ro = i >> 3, c8 = i & 7;
      uint4 v = *reinterpret_cast<const uint4*>(
          WT + (size_t)ro * LDT + (size_t)(kc0 + t) * 64 + 8 * c8);
      int boff = (ro * 128 + c8 * 16) ^ ((ro & 7) << 4);
      *reinterpret_cast<uint4*>(reinterpret_cast<char*>(Whs[buf]) + boff) = v;
    }
  };
  float4v acc[NCT];
#pragma unroll
  for (int ct = 0; ct < NCT; ++ct) acc[ct] = {0.f, 0.f, 0.f, 0.f};
  float4v accs = {0.f, 0.f, 0.f, 0.f};
  stage(0, 0);
  __syncthreads();
  for (int t = 0; t < nch; ++t) {
    int buf = t & 1;
    if (t + 1 < nch) stage(t + 1, buf ^ 1);
    // ---- generate P A-frags in registers ----
    const unsigned long long bwr = Bw2[buf][r0 + li];
    const float f1v = F1s[r0 + li];
    short8v afr[2];
#pragma unroll
    for (int q = 0; q < 2; ++q) {
      int koff = 32 * q + 8 * g;
      unsigned bits = (unsigned)(bwr >> koff) & 0xffu;
      const float4 fa = *reinterpret_cast<const float4*>(&F2d[buf][koff]);
      const float4 fb = *reinterpret_cast<const float4*>(&F2d[buf][koff + 4]);
      float f2v[8] = {fa.x, fa.y, fa.z, fa.w, fb.x, fb.y, fb.z, fb.w};
#pragma unroll
      for (int e = 0; e < 8; ++e) {
        float tt = f1v + f2v[e];
        tt = fmaxf(tt, ALPHA * tt);
        tt = (bits & (1u << e)) ? tt : -1.0e30f;   // exp2(-1e30) = 0
        afr[q][e] = f2b(__builtin_amdgcn_exp2f(tt));
      }
    }
    // ---- B-frags + MFMA (incl. rowsum tile) ----
#pragma unroll
    for (int ct = 0; ct < NCT; ++ct) {
      int orow = ct * 16 + li;
#pragma unroll
      for (int q = 0; q < 2; ++q) {
        int boff = (orow * 128 + q * 64 + 16 * g) ^ ((li & 7) << 4);
        short8v bfr = *reinterpret_cast<const short8v*>(
            reinterpret_cast<const char*>(Whs[buf]) + boff);
        acc[ct] = __builtin_amdgcn_mfma_f32_16x16x32_bf16(afr[q], bfr, acc[ct], 0, 0, 0);
      }
    }
    accs = __builtin_amdgcn_mfma_f32_16x16x32_bf16(afr[0], onesf, accs, 0, 0, 0);
    accs = __builtin_amdgcn_mfma_f32_16x16x32_bf16(afr[1], onesf, accs, 0, 0, 0);
    __syncthreads();
  }
  // ---- write partials ----
  float* Cp = Cpart + ((size_t)ks * 8 + z) * NNODE * O;
#pragma unroll
  for (int j = 0; j < 4; ++j) {
    int n = n0 + r0 + 4 * g + j;
    if (n < NNODE) {
#pragma unroll
      for (int ct = 0; ct < NCT; ++ct)
        Cp[(size_t)n * O + ct * 16 + li] = acc[ct][j];
    }
  }
  if (li == 0) {
#pragma unroll
    for (int j = 0; j < 4; ++j) {
      int n = n0 + r0 + 4 * g + j;
      if (n < NNODE) rsum[((size_t)ks * 8 + z) * NNODE + n] = accs[j];
    }
  }
}

// ---------------- PV reduce: sum partials, normalize, ELU, head-concat ----------------
template <int O, int KS, bool WB16>
__global__ __launch_bounds__(256)
void k_pvred(const float* __restrict__ Cpart, const float* __restrict__ rsum,
             float* __restrict__ Cf, unsigned short* __restrict__ Cb) {
  constexpr int C4 = O / 4;
  int idx = blockIdx.x * 256 + threadIdx.x;
  if (idx >= 8 * NNODE * C4) return;
  int zn = idx / C4, c4 = idx % C4;
  int z = zn / NNODE, n = zn % NNODE;
  int a = z >> 2, h = z & 3;
  float s = 0.f;
#pragma unroll
  for (int k = 0; k < KS; ++k) s += rsum[(size_t)k * 8 * NNODE + zn];
  float inv = (s > 0.f) ? 1.f / s : 0.f;
  float accv[4] = {0.f, 0.f, 0.f, 0.f};
#pragma unroll
  for (int k = 0; k < KS; ++k) {
    float4 v = *reinterpret_cast<const float4*>(
        Cpart + (size_t)k * 8 * NNODE * O + (size_t)zn * O + 4 * c4);
    accv[0] += v.x; accv[1] += v.y; accv[2] += v.z; accv[3] += v.w;
  }
  size_t base = ((size_t)a * NNODE + n) * (4 * O) + (size_t)h * O + 4 * c4;
  if (WB16) {
    short4v w;
#pragma unroll
    for (int j = 0; j < 4; ++j) {
      float v = accv[j] * inv;
      v = v > 0.f ? v : (__expf(v) - 1.f);
      w[j] = f2b(v);
    }
    *reinterpret_cast<short4v*>(Cb + base) = w;
  } else {
    float4 w;
    float* wp = &w.x;
#pragma unroll
    for (int j = 0; j < 4; ++j) {
      float v = accv[j] * inv;
      wp[j] = v > 0.f ? v : (__expf(v) - 1.f);
    }
    *reinterpret_cast<float4*>(Cf + base) = w;
  }
}

// ---------------- generic tiled fp32 GEMM (tail layers) ----------------
template <int BM, int BN, int BK, int TM, int TN, bool BT, int ACT>
__global__ __launch_bounds__((BM / TM) * (BN / TN))
void k_gemm(const float* __restrict__ A, long long boffA, int ldA,
            const float* __restrict__ B, long long boffB,
            const float* __restrict__ bias,
            float* __restrict__ C, long long boffC, int ldC,
            int M, int N, int K) {
  constexpr int NT = (BM / TM) * (BN / TN);
  constexpr int NCG = BN / TN;
  const int z = blockIdx.z;
  A += boffA * z;
  B += boffB * z;
  C += boffC * z;
  const int m0 = blockIdx.x * BM;
  const int n0 = blockIdx.y * BN;
  __shared__ float As[BK][BM + 4];
  __shared__ float Bs[BK][BN + 4];
  const int tid = threadIdx.x;
  const int trow = tid / NCG, tcol = tid % NCG;
  float acc[TM][TN] = {};
  for (int k0 = 0; k0 < K; k0 += BK) {
    for (int i = tid; i < BM * BK; i += NT) {
      int r = i / BK, c = i % BK;
      int gm = m0 + r;
      As[c][r] = (gm < M) ? A[(size_t)gm * ldA + (k0 + c)] : 0.f;
    }
    if (!BT) {
      for (int i = tid; i < BK * BN; i += NT) {
        int r = i / BN, c = i % BN;
        Bs[r][c] = B[(size_t)(k0 + r) * N + (n0 + c)];
      }
    } else {
      for (int i = tid; i < BK * BN; i += NT) {
        int r = i % BK, c = i / BK;
        Bs[r][c] = B[(size_t)(n0 + c) * K + (k0 + r)];
      }
    }
    __syncthreads();
#pragma unroll 8
    for (int kk = 0; kk < BK; ++kk) {
      float ar[TM], br[TN];
#pragma unroll
      for (int i2 = 0; i2 < TM; ++i2) ar[i2] = As[kk][trow * TM + i2];
#pragma unroll
      for (int j = 0; j < TN; ++j) br[j] = Bs[kk][tcol * TN + j];
#pragma unroll
      for (int i2 = 0; i2 < TM; ++i2)
#pragma unroll
        for (int j = 0; j < TN; ++j)
          acc[i2][j] = fmaf(ar[i2], br[j], acc[i2][j]);
    }
    __syncthreads();
  }
#pragma unroll
  for (int i2 = 0; i2 < TM; ++i2) {
    int gm = m0 + trow * TM + i2;
    if (gm >= M) continue;
#pragma unroll
    for (int j = 0; j < TN; ++j) {
      int gn = n0 + tcol * TN + j;
      float v = acc[i2][j];
      if (bias) v += bias[gn];
      if (ACT == 1) v = v > 0.f ? v : (__expf(v) - 1.f);
      C[(size_t)gm * ldC + gn] = v;
    }
  }
}

// ---------------- log_softmax rows of 8 ----------------
__global__ __launch_bounds__(256)
void k_lsm(const float* __restrict__ out2, float* __restrict__ out) {
  int n = blockIdx.x * blockDim.x + threadIdx.x;
  if (n >= NNODE) return;
  const float* r = out2 + (size_t)n * 8;
  float mx = r[0];
#pragma unroll
  for (int j = 1; j < 8; ++j) mx = fmaxf(mx, r[j]);
  float s = 0.f;
#pragma unroll
  for (int j = 0; j < 8; ++j) s += __expf(r[j] - mx);
  float ls = __logf(s) + mx;
#pragma unroll
  for (int j = 0; j < 8; ++j) out[(size_t)n * 8 + j] = r[j] - ls;
}

// ---------------- L1 scalar ----------------
__global__ __launch_bounds__(256)
void k_l1(const float* __restrict__ wfus1, const float* __restrict__ wfus2,
          float* __restrict__ o) {
  __shared__ float red[256];
  int tid = threadIdx.x;
  float s1 = 0.f, s2 = 0.f;
  for (int i = tid; i < 64 * 128; i += 256) s1 += fabsf(wfus1[i]);
  if (tid < 128) s2 = fabsf(wfus2[tid]);
  red[tid] = s1 / 8192.f + s2 / 128.f;
  __syncthreads();
  for (int off = 128; off; off >>= 1) {
    if (tid < off) red[tid] += red[tid + off];
    __syncthreads();
  }
  if (tid == 0) o[0] = red[0];
}

extern "C" void kernel_launch(void* const* d_in, const int* in_sizes, int n_in,
                              void* d_out, int out_size, void* d_ws, size_t ws_size,
                              hipStream_t stream) {
  const float* x = (const float*)d_in[0];
  const int* adj = (const int*)d_in[1];
  const float* W1 = (const float*)d_in[2];
  const float* a1 = (const float*)d_in[3];
  const float* W2 = (const float*)d_in[4];
  const float* a2 = (const float*)d_in[5];
  const float* wint1 = (const float*)d_in[6];
  const float* bint1 = (const float*)d_in[7];
  const float* wfus1 = (const float*)d_in[8];
  const float* bfus1 = (const float*)d_in[9];
  const float* wint2 = (const float*)d_in[10];
  const float* bint2 = (const float*)d_in[11];
  const float* wfus2 = (const float*)d_in[12];
  const float* bfus2 = (const float*)d_in[13];
  float* out = (float*)d_out;

  // workspace layout (float offsets); peak 5,517,600 floats = 22.1 MB
  float* W = (float*)d_ws;
  unsigned long long* bm = (unsigned long long*)d_ws;          // 0..564000
  unsigned short* xb = (unsigned short*)(W + 564000);          // [3000][512] bf16, dead after xw1
  unsigned short* h1catb = (unsigned short*)(W + 564000);      // [2][3000][256] bf16 (after reduce1)
  float* h2cat = W + 564000;                                   // [2][3000][128] f32 (after reduce2)
  unsigned short* W1Tb = (unsigned short*)(W + 1332000);       // [8][64][512] bf16
  unsigned short* wint1b = (unsigned short*)(W + 1463072);     // [64][256] bf16
  unsigned short* wfus1b = (unsigned short*)(W + 1471264);     // [64][128] bf16
  unsigned short* W2Tb = (unsigned short*)(W + 1475360);       // [8][32][64] bf16
  float* f1b = W + 1483552;                                    // [8][3000]
  float* f2g = W + 1507552;                                    // [8][3000]
  unsigned short* WhT1 = (unsigned short*)(W + 1531552);       // [8][64][3008] bf16, dead after pvs1
  unsigned short* t1b = (unsigned short*)(W + 1531552);        // [3000][128] bf16 (after int1)
  unsigned short* out1b = (unsigned short*)(W + 1723552);      // [3000][64] bf16
  unsigned short* WhT2 = (unsigned short*)(W + 1819552);       // [8][32][3008] bf16
  float* t2 = W + 2301600;                                     // [3000][16]
  float* out2 = W + 2349600;                                   // [3000][8]
  float* rsumw = W + 2373600;                                  // [3][8][3000]
  float* Cpart = W + 2445600;                                  // [2][8][3000][64] / [3][8][3000][32]

  // adj -> bitmask
  k_bitmask<<<dim3(1500), 256, 0, stream>>>(adj, bm);
  // casts / weight transposes
  k_cast<<<dim3(750), 256, 0, stream>>>(x, xb, 192000);
  k_wt<64><<<dim3(8, 8), 256, 0, stream>>>(W1, W1Tb, 512, 512);
  k_cast<<<dim3(8), 256, 0, stream>>>(wint1, wint1b, 2048);
  k_cast<<<dim3(4), 256, 0, stream>>>(wfus1, wfus1b, 1024);
  k_wt<32><<<dim3(1, 8), 256, 0, stream>>>(W2, W2Tb, 64, 64);

  // stage 1: Wh1 + f1/f2 (pre-scaled) + WhT1, fused
  k_xw<64, 512, 1, 0><<<dim3(94, 1, 8), 128, 0, stream>>>(
      xb, 0, W1Tb, 64 * 512, a1, WhT1, (long long)64 * LDT, f1b, f2g, 0, 0);
  // PV stage 1 (K-split 2, 32-row blocks) -> partials -> h1catb bf16
  k_pvs<64, 24><<<dim3(94, 2, 8), 128, 0, stream>>>(WhT1, f1b, f2g, bm, Cpart, rsumw);
  k_pvred<64, 2, true><<<dim3(1500), 256, 0, stream>>>(Cpart, rsumw, nullptr, h1catb);
  // int1 -> t1b bf16
  k_xw<32, 256, 0, 1><<<dim3(94, 2, 2), 128, 0, stream>>>(
      h1catb, (long long)NNODE * 256, wint1b, 0, bint1, t1b, 0, nullptr, nullptr, 64, 128);
  // fus1 -> out1b bf16
  k_xw<32, 128, 0, 0><<<dim3(94, 2, 1), 128, 0, stream>>>(
      t1b, 0, wfus1b, 0, bfus1, out1b, 0, nullptr, nullptr, 0, 64);

  // stage 2: Wh2 + f1/f2 (pre-scaled) + WhT2, fused
  k_xw<32, 64, 1, 0><<<dim3(94, 1, 8), 128, 0, stream>>>(
      out1b, 0, W2Tb, 32 * 64, a2, WhT2, (long long)32 * LDT, f1b, f2g, 0, 0);
  // PV stage 2 (K-split 3, 32-row blocks) -> partials -> h2cat fp32
  k_pvs<32, 16><<<dim3(94, 3, 8), 128, 0, stream>>>(WhT2, f1b, f2g, bm, Cpart, rsumw);
  k_pvred<32, 3, false><<<dim3(750), 256, 0, stream>>>(Cpart, rsumw, h2cat, nullptr);

  // int2 / fus2 (fp32 tail)
  k_gemm<32, 8, 32, 2, 1, true, 1><<<dim3(94, 1, 2), 128, 0, stream>>>(
      h2cat, (long long)NNODE * 128, 128, wint2, 0, bint2, t2, 8, 16, NNODE, 8, 128);
  k_gemm<32, 8, 16, 2, 1, true, 0><<<dim3(94, 1, 1), 128, 0, stream>>>(
      t2, 0, 16, wfus2, 0, bfus2, out2, 0, 8, NNODE, 8, 16);

  // log_softmax + L1
  k_lsm<<<dim3((NNODE + 255) / 256), 256, 0, stream>>>(out2, out);
  k_l1<<<dim3(1), 256, 0, stream>>>(wfus1, wfus2, out + 24000);
}

// Round 8
// 174.317 us; speedup vs baseline: 1.2030x; 1.2030x over previous
//
#include <hip/hip_runtime.h>
#include <hip/hip_bf16.h>
#include <math.h>

#define NNODE 3000
#define NCHUNK 47  // ceil(3000/64)
#define ALPHA 0.2f
#define LDT 3008   // padded m-stride of WhT (bf16)
#define LOG2E 1.4426950408889634f

typedef __attribute__((ext_vector_type(8))) short short8v;
typedef __attribute__((ext_vector_type(4))) short short4v;
typedef __attribute__((ext_vector_type(4))) float float4v;

static __device__ __forceinline__ short f2b(float x) {
  __hip_bfloat16 b = __float2bfloat16(x);
  return *reinterpret_cast<short*>(&b);
}
static __device__ __forceinline__ float b2f(unsigned short u) {
  unsigned v = ((unsigned)u) << 16;
  return *reinterpret_cast<float*>(&v);
}

// ---------------- adj -> bitmask ----------------
__global__ __launch_bounds__(256)
void k_bitmask(const int* __restrict__ adj, unsigned long long* __restrict__ bm) {
  int row = blockIdx.x * 4 + (threadIdx.x >> 6);
  int lane = threadIdx.x & 63;
  if (row >= 2 * NNODE) return;
  const int* arow = adj + (size_t)row * NNODE;
  unsigned long long* brow = bm + (size_t)row * NCHUNK;
  for (int c = 0; c < NCHUNK; ++c) {
    int m = c * 64 + lane;
    int v = (m < NNODE) ? (arow[m] > 0) : 0;
    unsigned long long mask = __ballot(v);
    if (lane == 0) brow[c] = mask;
  }
}

// ---------------- fp32 -> bf16 cast (8 elems/thread) ----------------
__global__ __launch_bounds__(256)
void k_cast(const float* __restrict__ src, unsigned short* __restrict__ dst,
            int count8) {
  int i = blockIdx.x * 256 + threadIdx.x;
  if (i >= count8) return;
  float4 va = reinterpret_cast<const float4*>(src)[2 * i];
  float4 vb = reinterpret_cast<const float4*>(src)[2 * i + 1];
  short8v w;
  w[0] = f2b(va.x); w[1] = f2b(va.y); w[2] = f2b(va.z); w[3] = f2b(va.w);
  w[4] = f2b(vb.x); w[5] = f2b(vb.y); w[6] = f2b(vb.z); w[7] = f2b(vb.w);
  reinterpret_cast<short8v*>(dst)[i] = w;
}

// ------- weight transpose+cast: src [z][rows][O] f32 -> dst [z][O][ldT] bf16 -------
template <int O>
__global__ __launch_bounds__(256)
void k_wt(const float* __restrict__ src, unsigned short* __restrict__ dst,
          int rows, int ldT) {
  const int z = blockIdx.y;
  const int m0 = blockIdx.x * 64;
  src += (size_t)z * rows * O;
  dst += (size_t)z * O * ldT;
  __shared__ float Lw[64][O + 4];
  const int tid = threadIdx.x;
  for (int idx = tid; idx < 64 * (O / 4); idx += 256) {
    int m = idx / (O / 4), oc = idx % (O / 4);
    float4 v = make_float4(0.f, 0.f, 0.f, 0.f);
    if (m0 + m < rows)
      v = *reinterpret_cast<const float4*>(&src[(size_t)(m0 + m) * O + 4 * oc]);
    *reinterpret_cast<float4*>(&Lw[m][4 * oc]) = v;
  }
  __syncthreads();
  const int o = tid & (O - 1);
  for (int mc = tid / O; mc < 8; mc += 256 / O) {
    short8v w;
#pragma unroll
    for (int j = 0; j < 8; ++j) w[j] = f2b(Lw[8 * mc + j][o]);
    *reinterpret_cast<short8v*>(&dst[(size_t)o * ldT + m0 + 8 * mc]) = w;
  }
}

// ---------------- bf16 MFMA GEMM, 32 rows x OW cols per 128-thr block ----------------
template <int OW, int KC, int MODE, int ACT>
__global__ __launch_bounds__(128)
void k_xw(const unsigned short* __restrict__ Ab, long long boffA,
          const unsigned short* __restrict__ Bb, long long boffB,
          const float* __restrict__ aux,
          unsigned short* __restrict__ Wo,
          long long boffW,
          float* __restrict__ f1o, float* __restrict__ f2o,
          int colStrideZ, int ldC) {
  constexpr int NCT = OW / 16;
  const int z = blockIdx.z;
  const int n0 = blockIdx.x * 32;
  const int ocol0 = blockIdx.y * OW;
  const unsigned short* A = Ab + boffA * z;
  const unsigned short* B = Bb + boffB * z;
  const int tid = threadIdx.x;
  const int l = tid & 63, g = l >> 4, li = l & 15;
  const int r0 = 16 * (tid >> 6);
  __shared__ __align__(16) unsigned short As[32 * 64];
  __shared__ __align__(16) unsigned short Bs[OW * 64];
  float4v acc[NCT];
#pragma unroll
  for (int ct = 0; ct < NCT; ++ct) acc[ct] = {0.f, 0.f, 0.f, 0.f};
  for (int k0 = 0; k0 < KC; k0 += 64) {
    for (int i = tid; i < 256; i += 128) {
      int r = i >> 3, c8 = i & 7;
      uint4 v = {0u, 0u, 0u, 0u};
      if (n0 + r < NNODE)
        v = *reinterpret_cast<const uint4*>(A + (size_t)(n0 + r) * KC + k0 + 8 * c8);
      int boff = (r * 128 + c8 * 16) ^ ((r & 7) << 4);
      *reinterpret_cast<uint4*>(reinterpret_cast<char*>(As) + boff) = v;
    }
    for (int i = tid; i < OW * 8; i += 128) {
      int ro = i >> 3, c8 = i & 7;
      uint4 v = *reinterpret_cast<const uint4*>(B + (size_t)(ocol0 + ro) * KC + k0 + 8 * c8);
      int boff = (ro * 128 + c8 * 16) ^ ((ro & 7) << 4);
      *reinterpret_cast<uint4*>(reinterpret_cast<char*>(Bs) + boff) = v;
    }
    __syncthreads();
#pragma unroll
    for (int q = 0; q < 2; ++q) {
      int aoff = ((r0 + li) * 128 + q * 64 + 16 * g) ^ ((li & 7) << 4);
      short8v afr = *reinterpret_cast<const short8v*>(
          reinterpret_cast<const char*>(As) + aoff);
#pragma unroll
      for (int ct = 0; ct < NCT; ++ct) {
        int orow = ct * 16 + li;
        int boff = (orow * 128 + q * 64 + 16 * g) ^ ((li & 7) << 4);
        short8v bfr = *reinterpret_cast<const short8v*>(
            reinterpret_cast<const char*>(Bs) + boff);
        acc[ct] = __builtin_amdgcn_mfma_f32_16x16x32_bf16(afr, bfr, acc[ct], 0, 0, 0);
      }
    }
    __syncthreads();
  }
  if (MODE == 1) {
    const float* av = aux + (size_t)z * 2 * OW;
    float p1[4] = {0.f, 0.f, 0.f, 0.f}, p2[4] = {0.f, 0.f, 0.f, 0.f};
#pragma unroll
    for (int ct = 0; ct < NCT; ++ct) {
      float a1v = av[ct * 16 + li];
      float a2v = av[OW + ct * 16 + li];
#pragma unroll
      for (int j = 0; j < 4; ++j) {
        p1[j] += acc[ct][j] * a1v;
        p2[j] += acc[ct][j] * a2v;
      }
    }
#pragma unroll
    for (int off = 1; off < 16; off <<= 1) {
#pragma unroll
      for (int j = 0; j < 4; ++j) {
        p1[j] += __shfl_xor(p1[j], off);
        p2[j] += __shfl_xor(p2[j], off);
      }
    }
    unsigned short* WT = Wo + boffW * z;
#pragma unroll
    for (int ct = 0; ct < NCT; ++ct) {
      short4v w;
#pragma unroll
      for (int j = 0; j < 4; ++j) w[j] = f2b(acc[ct][j]);
      *reinterpret_cast<short4v*>(
          &WT[(size_t)(ocol0 + ct * 16 + li) * LDT + n0 + r0 + 4 * g]) = w;
    }
    if (li == 0) {
#pragma unroll
      for (int j = 0; j < 4; ++j) {
        int n = n0 + r0 + 4 * g + j;
        if (n < NNODE) {
          // pre-scaled by log2(e): score pipeline uses exp2 directly
          f1o[(size_t)z * NNODE + n] = p1[j] * LOG2E;
          f2o[(size_t)z * NNODE + n] = p2[j] * LOG2E;
        }
      }
    }
  } else {
#pragma unroll
    for (int ct = 0; ct < NCT; ++ct) {
      float b = aux[ocol0 + ct * 16 + li];
#pragma unroll
      for (int j = 0; j < 4; ++j) {
        int n = n0 + r0 + 4 * g + j;
        if (n < NNODE) {
          float v = acc[ct][j] + b;
          if (ACT == 1) v = v > 0.f ? v : (__expf(v) - 1.f);
          Wo[(size_t)n * ldC + z * colStrideZ + ocol0 + ct * 16 + li] = (unsigned short)f2b(v);
        }
      }
    }
  }
}

// ---------------- MFMA PV, K-split partials: 64 rows, 256 thr, 4 waves ----------------
// Per-tile double-buffered Wh tile + bitmask + f2 (small LDS). exp2 scores with
// mask folded into exponent. Rowsum via MFMA against register ones-fragment.
// Partials: bf16 (stage1) or fp32 (stage2).
template <int O, int CPS, bool PB16>
__global__ __launch_bounds__(256)
void k_pvp(const unsigned short* __restrict__ WhT,
           const float* __restrict__ f1, const float* __restrict__ f2,
           const unsigned long long* __restrict__ bm,
           void* __restrict__ Cpart, float* __restrict__ rsum) {
  constexpr int NCT = O / 16;
  const int z = blockIdx.z, a = z >> 2;
  const int ks = blockIdx.y;
  const int n0 = blockIdx.x * 64;
  const int kc0 = ks * CPS;
  const int nch = (NCHUNK - kc0 < CPS) ? (NCHUNK - kc0) : CPS;
  const int tid = threadIdx.x;
  const int l = tid & 63, li = l & 15, g = l >> 4;
  const int r0 = 16 * (tid >> 6);  // 0,16,32,48 (4 waves)
  const unsigned short* WT = WhT + (size_t)z * O * LDT;
  const float* f2B = f2 + (size_t)z * NNODE;
  const unsigned long long* bmA = bm + (size_t)a * NNODE * NCHUNK;
  __shared__ __align__(16) unsigned short Whs[2][O * 64];
  __shared__ __align__(16) float F2d[2][64];
  __shared__ unsigned long long Bw2[2][64];
  __shared__ float F1s[64];
  if (tid < 64) {
    int n = n0 + tid;
    F1s[tid] = (n < NNODE) ? f1[(size_t)z * NNODE + n] : 0.f;
  }
  // ones-fragment: bf16 1.0 in B col 0 (lanes li==0)
  short8v onesf;
  {
    short ov = (li == 0) ? (short)0x3F80 : (short)0;
#pragma unroll
    for (int e = 0; e < 8; ++e) onesf[e] = ov;
  }
  auto stage = [&](int t, int buf) {
    if (tid < 64) {
      int n = n0 + tid;
      Bw2[buf][tid] = (n < NNODE) ? bmA[(size_t)n * NCHUNK + kc0 + t] : 0ULL;
    } else if (tid < 128) {
      int m = (kc0 + t) * 64 + (tid - 64);
      F2d[buf][tid - 64] = (m < NNODE) ? f2B[m] : 0.f;
    }
    for (int i = tid; i < O * 8; i += 256) {
      int ro = i >> 3, c8 = i & 7;
      uint4 v = *reinterpret_cast<const uint4*>(
          WT + (size_t)ro * LDT + (size_t)(kc0 + t) * 64 + 8 * c8);
      int boff = (ro * 128 + c8 * 16) ^ ((ro & 7) << 4);
      *reinterpret_cast<uint4*>(reinterpret_cast<char*>(Whs[buf]) + boff) = v;
    }
  };
  float4v acc[NCT];
#pragma unroll
  for (int ct = 0; ct < NCT; ++ct) acc[ct] = {0.f, 0.f, 0.f, 0.f};
  float4v accs = {0.f, 0.f, 0.f, 0.f};
  stage(0, 0);
  __syncthreads();
  for (int t = 0; t < nch; ++t) {
    int buf = t & 1;
    if (t + 1 < nch) stage(t + 1, buf ^ 1);
    // ---- generate P A-frags in registers ----
    const unsigned long long bwr = Bw2[buf][r0 + li];
    const float f1v = F1s[r0 + li];
    short8v afr[2];
#pragma unroll
    for (int q = 0; q < 2; ++q) {
      int koff = 32 * q + 8 * g;
      unsigned bits = (unsigned)(bwr >> koff) & 0xffu;
      const float4 fa = *reinterpret_cast<const float4*>(&F2d[buf][koff]);
      const float4 fb = *reinterpret_cast<const float4*>(&F2d[buf][koff + 4]);
      float f2v[8] = {fa.x, fa.y, fa.z, fa.w, fb.x, fb.y, fb.z, fb.w};
#pragma unroll
      for (int e = 0; e < 8; ++e) {
        float tt = f1v + f2v[e];
        tt = fmaxf(tt, ALPHA * tt);
        tt = (bits & (1u << e)) ? tt : -1.0e30f;   // exp2(-1e30) = 0
        afr[q][e] = f2b(__builtin_amdgcn_exp2f(tt));
      }
    }
    // ---- B-frags + MFMA (+rowsum MFMA) ----
#pragma unroll
    for (int ct = 0; ct < NCT; ++ct) {
      int orow = ct * 16 + li;
#pragma unroll
      for (int q = 0; q < 2; ++q) {
        int boff = (orow * 128 + q * 64 + 16 * g) ^ ((li & 7) << 4);
        short8v bfr = *reinterpret_cast<const short8v*>(
            reinterpret_cast<const char*>(Whs[buf]) + boff);
        acc[ct] = __builtin_amdgcn_mfma_f32_16x16x32_bf16(afr[q], bfr, acc[ct], 0, 0, 0);
      }
    }
    accs = __builtin_amdgcn_mfma_f32_16x16x32_bf16(afr[0], onesf, accs, 0, 0, 0);
    accs = __builtin_amdgcn_mfma_f32_16x16x32_bf16(afr[1], onesf, accs, 0, 0, 0);
    __syncthreads();
  }
  // ---- write partials ----
  if (PB16) {
    unsigned short* Cp = (unsigned short*)Cpart + ((size_t)ks * 8 + z) * NNODE * O;
#pragma unroll
    for (int j = 0; j < 4; ++j) {
      int n = n0 + r0 + 4 * g + j;
      if (n < NNODE) {
#pragma unroll
        for (int ct = 0; ct < NCT; ++ct)
          Cp[(size_t)n * O + ct * 16 + li] = (unsigned short)f2b(acc[ct][j]);
      }
    }
  } else {
    float* Cp = (float*)Cpart + ((size_t)ks * 8 + z) * NNODE * O;
#pragma unroll
    for (int j = 0; j < 4; ++j) {
      int n = n0 + r0 + 4 * g + j;
      if (n < NNODE) {
#pragma unroll
        for (int ct = 0; ct < NCT; ++ct)
          Cp[(size_t)n * O + ct * 16 + li] = acc[ct][j];
      }
    }
  }
  if (li == 0) {
#pragma unroll
    for (int j = 0; j < 4; ++j) {
      int n = n0 + r0 + 4 * g + j;
      if (n < NNODE) rsum[((size_t)ks * 8 + z) * NNODE + n] = accs[j];
    }
  }
}

// ---------------- PV reduce: sum partials, normalize, ELU, head-concat ----------------
template <int O, int KS, bool PB16, bool WB16>
__global__ __launch_bounds__(256)
void k_pvred(const void* __restrict__ Cpart, const float* __restrict__ rsum,
             float* __restrict__ Cf, unsigned short* __restrict__ Cb) {
  constexpr int C4 = O / 4;
  int idx = blockIdx.x * 256 + threadIdx.x;
  if (idx >= 8 * NNODE * C4) return;
  int zn = idx / C4, c4 = idx % C4;
  int z = zn / NNODE, n = zn % NNODE;
  int a = z >> 2, h = z & 3;
  float s = 0.f;
#pragma unroll
  for (int k = 0; k < KS; ++k) s += rsum[(size_t)k * 8 * NNODE + zn];
  float inv = (s > 0.f) ? 1.f / s : 0.f;
  float accv[4] = {0.f, 0.f, 0.f, 0.f};
#pragma unroll
  for (int k = 0; k < KS; ++k) {
    if (PB16) {
      short4v v = *reinterpret_cast<const short4v*>(
          (const unsigned short*)Cpart + (size_t)k * 8 * NNODE * O + (size_t)zn * O + 4 * c4);
#pragma unroll
      for (int j = 0; j < 4; ++j) accv[j] += b2f((unsigned short)v[j]);
    } else {
      float4 v = *reinterpret_cast<const float4*>(
          (const float*)Cpart + (size_t)k * 8 * NNODE * O + (size_t)zn * O + 4 * c4);
      accv[0] += v.x; accv[1] += v.y; accv[2] += v.z; accv[3] += v.w;
    }
  }
  size_t base = ((size_t)a * NNODE + n) * (4 * O) + (size_t)h * O + 4 * c4;
  if (WB16) {
    short4v w;
#pragma unroll
    for (int j = 0; j < 4; ++j) {
      float v = accv[j] * inv;
      v = v > 0.f ? v : (__expf(v) - 1.f);
      w[j] = f2b(v);
    }
    *reinterpret_cast<short4v*>(Cb + base) = w;
  } else {
    float4 w;
    float* wp = &w.x;
#pragma unroll
    for (int j = 0; j < 4; ++j) {
      float v = accv[j] * inv;
      wp[j] = v > 0.f ? v : (__expf(v) - 1.f);
    }
    *reinterpret_cast<float4*>(Cf + base) = w;
  }
}

// ---------------- generic tiled fp32 GEMM (tail layers) ----------------
template <int BM, int BN, int BK, int TM, int TN, bool BT, int ACT>
__global__ __launch_bounds__((BM / TM) * (BN / TN))
void k_gemm(const float* __restrict__ A, long long boffA, int ldA,
            const float* __restrict__ B, long long boffB,
            const float* __restrict__ bias,
            float* __restrict__ C, long long boffC, int ldC,
            int M, int N, int K) {
  constexpr int NT = (BM / TM) * (BN / TN);
  constexpr int NCG = BN / TN;
  const int z = blockIdx.z;
  A += boffA * z;
  B += boffB * z;
  C += boffC * z;
  const int m0 = blockIdx.x * BM;
  const int n0 = blockIdx.y * BN;
  __shared__ float As[BK][BM + 4];
  __shared__ float Bs[BK][BN + 4];
  const int tid = threadIdx.x;
  const int trow = tid / NCG, tcol = tid % NCG;
  float acc[TM][TN] = {};
  for (int k0 = 0; k0 < K; k0 += BK) {
    for (int i = tid; i < BM * BK; i += NT) {
      int r = i / BK, c = i % BK;
      int gm = m0 + r;
      As[c][r] = (gm < M) ? A[(size_t)gm * ldA + (k0 + c)] : 0.f;
    }
    if (!BT) {
      for (int i = tid; i < BK * BN; i += NT) {
        int r = i / BN, c = i % BN;
        Bs[r][c] = B[(size_t)(k0 + r) * N + (n0 + c)];
      }
    } else {
      for (int i = tid; i < BK * BN; i += NT) {
        int r = i % BK, c = i / BK;
        Bs[r][c] = B[(size_t)(n0 + c) * K + (k0 + r)];
      }
    }
    __syncthreads();
#pragma unroll 8
    for (int kk = 0; kk < BK; ++kk) {
      float ar[TM], br[TN];
#pragma unroll
      for (int i2 = 0; i2 < TM; ++i2) ar[i2] = As[kk][trow * TM + i2];
#pragma unroll
      for (int j = 0; j < TN; ++j) br[j] = Bs[kk][tcol * TN + j];
#pragma unroll
      for (int i2 = 0; i2 < TM; ++i2)
#pragma unroll
        for (int j = 0; j < TN; ++j)
          acc[i2][j] = fmaf(ar[i2], br[j], acc[i2][j]);
    }
    __syncthreads();
  }
#pragma unroll
  for (int i2 = 0; i2 < TM; ++i2) {
    int gm = m0 + trow * TM + i2;
    if (gm >= M) continue;
#pragma unroll
    for (int j = 0; j < TN; ++j) {
      int gn = n0 + tcol * TN + j;
      float v = acc[i2][j];
      if (bias) v += bias[gn];
      if (ACT == 1) v = v > 0.f ? v : (__expf(v) - 1.f);
      C[(size_t)gm * ldC + gn] = v;
    }
  }
}

// ---------------- log_softmax rows of 8 ----------------
__global__ __launch_bounds__(256)
void k_lsm(const float* __restrict__ out2, float* __restrict__ out) {
  int n = blockIdx.x * blockDim.x + threadIdx.x;
  if (n >= NNODE) return;
  const float* r = out2 + (size_t)n * 8;
  float mx = r[0];
#pragma unroll
  for (int j = 1; j < 8; ++j) mx = fmaxf(mx, r[j]);
  float s = 0.f;
#pragma unroll
  for (int j = 0; j < 8; ++j) s += __expf(r[j] - mx);
  float ls = __logf(s) + mx;
#pragma unroll
  for (int j = 0; j < 8; ++j) out[(size_t)n * 8 + j] = r[j] - ls;
}

// ---------------- L1 scalar ----------------
__global__ __launch_bounds__(256)
void k_l1(const float* __restrict__ wfus1, const float* __restrict__ wfus2,
          float* __restrict__ o) {
  __shared__ float red[256];
  int tid = threadIdx.x;
  float s1 = 0.f, s2 = 0.f;
  for (int i = tid; i < 64 * 128; i += 256) s1 += fabsf(wfus1[i]);
  if (tid < 128) s2 = fabsf(wfus2[tid]);
  red[tid] = s1 / 8192.f + s2 / 128.f;
  __syncthreads();
  for (int off = 128; off; off >>= 1) {
    if (tid < off) red[tid] += red[tid + off];
    __syncthreads();
  }
  if (tid == 0) o[0] = red[0];
}

extern "C" void kernel_launch(void* const* d_in, const int* in_sizes, int n_in,
                              void* d_out, int out_size, void* d_ws, size_t ws_size,
                              hipStream_t stream) {
  const float* x = (const float*)d_in[0];
  const int* adj = (const int*)d_in[1];
  const float* W1 = (const float*)d_in[2];
  const float* a1 = (const float*)d_in[3];
  const float* W2 = (const float*)d_in[4];
  const float* a2 = (const float*)d_in[5];
  const float* wint1 = (const float*)d_in[6];
  const float* bint1 = (const float*)d_in[7];
  const float* wfus1 = (const float*)d_in[8];
  const float* bfus1 = (const float*)d_in[9];
  const float* wint2 = (const float*)d_in[10];
  const float* bint2 = (const float*)d_in[11];
  const float* wfus2 = (const float*)d_in[12];
  const float* bfus2 = (const float*)d_in[13];
  float* out = (float*)d_out;

  // workspace layout (float offsets); peak 5,541,600 floats = 22.2 MB
  float* W = (float*)d_ws;
  unsigned long long* bm = (unsigned long long*)d_ws;          // 0..564000
  unsigned short* xb = (unsigned short*)(W + 564000);          // [3000][512] bf16, dead after xw1
  unsigned short* h1catb = (unsigned short*)(W + 564000);      // [2][3000][256] bf16 (after reduce1)
  float* h2cat = W + 564000;                                   // [2][3000][128] f32 (after reduce2)
  unsigned short* W1Tb = (unsigned short*)(W + 1332000);       // [8][64][512] bf16
  unsigned short* wint1b = (unsigned short*)(W + 1463072);     // [64][256] bf16
  unsigned short* wfus1b = (unsigned short*)(W + 1471264);     // [64][128] bf16
  unsigned short* W2Tb = (unsigned short*)(W + 1475360);       // [8][32][64] bf16
  float* f1b = W + 1483552;                                    // [8][3000]
  float* f2g = W + 1507552;                                    // [8][3000]
  unsigned short* WhT1 = (unsigned short*)(W + 1531552);       // [8][64][3008] bf16, dead after pvp1
  unsigned short* t1b = (unsigned short*)(W + 1531552);        // [3000][128] bf16 (after int1)
  unsigned short* out1b = (unsigned short*)(W + 1723552);      // [3000][64] bf16
  unsigned short* WhT2 = (unsigned short*)(W + 1819552);       // [8][32][3008] bf16
  float* t2 = W + 2301600;                                     // [3000][16]
  float* out2 = W + 2349600;                                   // [3000][8]
  float* rsumw = W + 2373600;                                  // [4][8][3000]
  void* Cpart = (void*)(W + 2469600);                          // bf16 [4][8][3000][64] / f32 [4][8][3000][32]

  // adj -> bitmask
  k_bitmask<<<dim3(1500), 256, 0, stream>>>(adj, bm);
  // casts / weight transposes
  k_cast<<<dim3(750), 256, 0, stream>>>(x, xb, 192000);
  k_wt<64><<<dim3(8, 8), 256, 0, stream>>>(W1, W1Tb, 512, 512);
  k_cast<<<dim3(8), 256, 0, stream>>>(wint1, wint1b, 2048);
  k_cast<<<dim3(4), 256, 0, stream>>>(wfus1, wfus1b, 1024);
  k_wt<32><<<dim3(1, 8), 256, 0, stream>>>(W2, W2Tb, 64, 64);

  // stage 1: Wh1 + f1/f2 (pre-scaled) + WhT1, fused
  k_xw<64, 512, 1, 0><<<dim3(94, 1, 8), 128, 0, stream>>>(
      xb, 0, W1Tb, 64 * 512, a1, WhT1, (long long)64 * LDT, f1b, f2g, 0, 0);
  // PV stage 1 (K-split 4, bf16 partials) -> h1catb bf16
  k_pvp<64, 12, true><<<dim3(47, 4, 8), 256, 0, stream>>>(WhT1, f1b, f2g, bm, Cpart, rsumw);
  k_pvred<64, 4, true, true><<<dim3(1500), 256, 0, stream>>>(Cpart, rsumw, nullptr, h1catb);
  // int1 -> t1b bf16
  k_xw<32, 256, 0, 1><<<dim3(94, 2, 2), 128, 0, stream>>>(
      h1catb, (long long)NNODE * 256, wint1b, 0, bint1, t1b, 0, nullptr, nullptr, 64, 128);
  // fus1 -> out1b bf16
  k_xw<32, 128, 0, 0><<<dim3(94, 2, 1), 128, 0, stream>>>(
      t1b, 0, wfus1b, 0, bfus1, out1b, 0, nullptr, nullptr, 0, 64);

  // stage 2: Wh2 + f1/f2 (pre-scaled) + WhT2, fused
  k_xw<32, 64, 1, 0><<<dim3(94, 1, 8), 128, 0, stream>>>(
      out1b, 0, W2Tb, 32 * 64, a2, WhT2, (long long)32 * LDT, f1b, f2g, 0, 0);
  // PV stage 2 (K-split 4, fp32 partials) -> h2cat fp32
  k_pvp<32, 12, false><<<dim3(47, 4, 8), 256, 0, stream>>>(WhT2, f1b, f2g, bm, Cpart, rsumw);
  k_pvred<32, 4, false, false><<<dim3(750), 256, 0, stream>>>(Cpart, rsumw, h2cat, nullptr);

  // int2 / fus2 (fp32 tail)
  k_gemm<32, 8, 32, 2, 1, true, 1><<<dim3(94, 1, 2), 128, 0, stream>>>(
      h2cat, (long long)NNODE * 128, 128, wint2, 0, bint2, t2, 8, 16, NNODE, 8, 128);
  k_gemm<32, 8, 16, 2, 1, true, 0><<<dim3(94, 1, 1), 128, 0, stream>>>(
      t2, 0, 16, wfus2, 0, bfus2, out2, 0, 8, NNODE, 8, 16);

  // log_softmax + L1
  k_lsm<<<dim3((NNODE + 255) / 256), 256, 0, stream>>>(out2, out);
  k_l1<<<dim3(1), 256, 0, stream>>>(wfus1, wfus2, out + 24000);
}

// Round 9
// 163.966 us; speedup vs baseline: 1.2790x; 1.0631x over previous
//
#include <hip/hip_runtime.h>
#include <hip/hip_bf16.h>
#include <math.h>

#define NNODE 3000
#define NCHUNK 47  // ceil(3000/64)
#define NBPR 376   // bytes per bitmask row (47*8)
#define ALPHA 0.2f
#define LDT 3008   // padded m-stride of WhT (bf16)
#define LOG2E 1.4426950408889634f

typedef __attribute__((ext_vector_type(8))) short short8v;
typedef __attribute__((ext_vector_type(4))) short short4v;
typedef __attribute__((ext_vector_type(4))) float float4v;

static __device__ __forceinline__ short f2b(float x) {
  __hip_bfloat16 b = __float2bfloat16(x);
  return *reinterpret_cast<short*>(&b);
}
static __device__ __forceinline__ float b2f(unsigned short u) {
  unsigned v = ((unsigned)u) << 16;
  return *reinterpret_cast<float*>(&v);
}

// ---------------- adj -> bitmask (byte-packed, ballot-free) ----------------
// byte b of row r covers m = 8b..8b+7 (bit j <-> m = 8b+j); little-endian u64
// assembly matches the consumer's (bm >> e) & 1 indexing. Pad byte 375 = 0.
__global__ __launch_bounds__(256)
void k_bitmask(const int* __restrict__ adj, unsigned char* __restrict__ bmb) {
  int idx = blockIdx.x * 256 + threadIdx.x;
  if (idx >= 2 * NNODE * NBPR) return;
  int row = idx / NBPR, b = idx % NBPR;
  unsigned char v = 0;
  if (b < 375) {
    const int* p = adj + (size_t)row * NNODE + 8 * b;
    int4 a0 = *reinterpret_cast<const int4*>(p);
    int4 a1 = *reinterpret_cast<const int4*>(p + 4);
    v = (unsigned char)((a0.x > 0) | ((a0.y > 0) << 1) | ((a0.z > 0) << 2) |
                        ((a0.w > 0) << 3) | ((a1.x > 0) << 4) | ((a1.y > 0) << 5) |
                        ((a1.z > 0) << 6) | ((a1.w > 0) << 7));
  }
  bmb[idx] = v;
}

// ---------------- fp32 -> bf16 cast (8 elems/thread) ----------------
__global__ __launch_bounds__(256)
void k_cast(const float* __restrict__ src, unsigned short* __restrict__ dst,
            int count8) {
  int i = blockIdx.x * 256 + threadIdx.x;
  if (i >= count8) return;
  float4 va = reinterpret_cast<const float4*>(src)[2 * i];
  float4 vb = reinterpret_cast<const float4*>(src)[2 * i + 1];
  short8v w;
  w[0] = f2b(va.x); w[1] = f2b(va.y); w[2] = f2b(va.z); w[3] = f2b(va.w);
  w[4] = f2b(vb.x); w[5] = f2b(vb.y); w[6] = f2b(vb.z); w[7] = f2b(vb.w);
  reinterpret_cast<short8v*>(dst)[i] = w;
}

// ------- weight transpose+cast: src [z][rows][O] f32 -> dst [z][O][ldT] bf16 -------
template <int O>
__global__ __launch_bounds__(256)
void k_wt(const float* __restrict__ src, unsigned short* __restrict__ dst,
          int rows, int ldT) {
  const int z = blockIdx.y;
  const int m0 = blockIdx.x * 64;
  src += (size_t)z * rows * O;
  dst += (size_t)z * O * ldT;
  __shared__ float Lw[64][O + 4];
  const int tid = threadIdx.x;
  for (int idx = tid; idx < 64 * (O / 4); idx += 256) {
    int m = idx / (O / 4), oc = idx % (O / 4);
    float4 v = make_float4(0.f, 0.f, 0.f, 0.f);
    if (m0 + m < rows)
      v = *reinterpret_cast<const float4*>(&src[(size_t)(m0 + m) * O + 4 * oc]);
    *reinterpret_cast<float4*>(&Lw[m][4 * oc]) = v;
  }
  __syncthreads();
  const int o = tid & (O - 1);
  for (int mc = tid / O; mc < 8; mc += 256 / O) {
    short8v w;
#pragma unroll
    for (int j = 0; j < 8; ++j) w[j] = f2b(Lw[8 * mc + j][o]);
    *reinterpret_cast<short8v*>(&dst[(size_t)o * ldT + m0 + 8 * mc]) = w;
  }
}

// ---------------- bf16 MFMA GEMM, 32 rows x OW cols per 128-thr block ----------------
template <int OW, int KC, int MODE, int ACT>
__global__ __launch_bounds__(128)
void k_xw(const unsigned short* __restrict__ Ab, long long boffA,
          const unsigned short* __restrict__ Bb, long long boffB,
          const float* __restrict__ aux,
          unsigned short* __restrict__ Wo,
          long long boffW,
          float* __restrict__ f1o, float* __restrict__ f2o,
          int colStrideZ, int ldC) {
  constexpr int NCT = OW / 16;
  const int z = blockIdx.z;
  const int n0 = blockIdx.x * 32;
  const int ocol0 = blockIdx.y * OW;
  const unsigned short* A = Ab + boffA * z;
  const unsigned short* B = Bb + boffB * z;
  const int tid = threadIdx.x;
  const int l = tid & 63, g = l >> 4, li = l & 15;
  const int r0 = 16 * (tid >> 6);
  __shared__ __align__(16) unsigned short As[32 * 64];
  __shared__ __align__(16) unsigned short Bs[OW * 64];
  float4v acc[NCT];
#pragma unroll
  for (int ct = 0; ct < NCT; ++ct) acc[ct] = {0.f, 0.f, 0.f, 0.f};
  for (int k0 = 0; k0 < KC; k0 += 64) {
    for (int i = tid; i < 256; i += 128) {
      int r = i >> 3, c8 = i & 7;
      uint4 v = {0u, 0u, 0u, 0u};
      if (n0 + r < NNODE)
        v = *reinterpret_cast<const uint4*>(A + (size_t)(n0 + r) * KC + k0 + 8 * c8);
      int boff = (r * 128 + c8 * 16) ^ ((r & 7) << 4);
      *reinterpret_cast<uint4*>(reinterpret_cast<char*>(As) + boff) = v;
    }
    for (int i = tid; i < OW * 8; i += 128) {
      int ro = i >> 3, c8 = i & 7;
      uint4 v = *reinterpret_cast<const uint4*>(B + (size_t)(ocol0 + ro) * KC + k0 + 8 * c8);
      int boff = (ro * 128 + c8 * 16) ^ ((ro & 7) << 4);
      *reinterpret_cast<uint4*>(reinterpret_cast<char*>(Bs) + boff) = v;
    }
    __syncthreads();
#pragma unroll
    for (int q = 0; q < 2; ++q) {
      int aoff = ((r0 + li) * 128 + q * 64 + 16 * g) ^ ((li & 7) << 4);
      short8v afr = *reinterpret_cast<const short8v*>(
          reinterpret_cast<const char*>(As) + aoff);
#pragma unroll
      for (int ct = 0; ct < NCT; ++ct) {
        int orow = ct * 16 + li;
        int boff = (orow * 128 + q * 64 + 16 * g) ^ ((li & 7) << 4);
        short8v bfr = *reinterpret_cast<const short8v*>(
            reinterpret_cast<const char*>(Bs) + boff);
        acc[ct] = __builtin_amdgcn_mfma_f32_16x16x32_bf16(afr, bfr, acc[ct], 0, 0, 0);
      }
    }
    __syncthreads();
  }
  if (MODE == 1) {
    const float* av = aux + (size_t)z * 2 * OW;
    float p1[4] = {0.f, 0.f, 0.f, 0.f}, p2[4] = {0.f, 0.f, 0.f, 0.f};
#pragma unroll
    for (int ct = 0; ct < NCT; ++ct) {
      float a1v = av[ct * 16 + li];
      float a2v = av[OW + ct * 16 + li];
#pragma unroll
      for (int j = 0; j < 4; ++j) {
        p1[j] += acc[ct][j] * a1v;
        p2[j] += acc[ct][j] * a2v;
      }
    }
#pragma unroll
    for (int off = 1; off < 16; off <<= 1) {
#pragma unroll
      for (int j = 0; j < 4; ++j) {
        p1[j] += __shfl_xor(p1[j], off);
        p2[j] += __shfl_xor(p2[j], off);
      }
    }
    unsigned short* WT = Wo + boffW * z;
#pragma unroll
    for (int ct = 0; ct < NCT; ++ct) {
      short4v w;
#pragma unroll
      for (int j = 0; j < 4; ++j) w[j] = f2b(acc[ct][j]);
      *reinterpret_cast<short4v*>(
          &WT[(size_t)(ocol0 + ct * 16 + li) * LDT + n0 + r0 + 4 * g]) = w;
    }
    if (li == 0) {
#pragma unroll
      for (int j = 0; j < 4; ++j) {
        int n = n0 + r0 + 4 * g + j;
        if (n < NNODE) {
          f1o[(size_t)z * NNODE + n] = p1[j] * LOG2E;
          f2o[(size_t)z * NNODE + n] = p2[j] * LOG2E;
        }
      }
    }
  } else {
#pragma unroll
    for (int ct = 0; ct < NCT; ++ct) {
      float b = aux[ocol0 + ct * 16 + li];
#pragma unroll
      for (int j = 0; j < 4; ++j) {
        int n = n0 + r0 + 4 * g + j;
        if (n < NNODE) {
          float v = acc[ct][j] + b;
          if (ACT == 1) v = v > 0.f ? v : (__expf(v) - 1.f);
          Wo[(size_t)n * ldC + z * colStrideZ + ocol0 + ct * 16 + li] = (unsigned short)f2b(v);
        }
      }
    }
  }
}

// ---------------- MFMA PV, K-split partials: 64 rows, 256 thr, 4 waves ----------------
template <int O, int CPS, bool PB16>
__global__ __launch_bounds__(256)
void k_pvp(const unsigned short* __restrict__ WhT,
           const float* __restrict__ f1, const float* __restrict__ f2,
           const unsigned long long* __restrict__ bm,
           void* __restrict__ Cpart, float* __restrict__ rsum) {
  constexpr int NCT = O / 16;
  const int z = blockIdx.z, a = z >> 2;
  const int ks = blockIdx.y;
  const int n0 = blockIdx.x * 64;
  const int kc0 = ks * CPS;
  const int nch = (NCHUNK - kc0 < CPS) ? (NCHUNK - kc0) : CPS;
  const int tid = threadIdx.x;
  const int l = tid & 63, li = l & 15, g = l >> 4;
  const int r0 = 16 * (tid >> 6);  // 0,16,32,48 (4 waves)
  const unsigned short* WT = WhT + (size_t)z * O * LDT;
  const float* f2B = f2 + (size_t)z * NNODE;
  const unsigned long long* bmA = bm + (size_t)a * NNODE * NCHUNK;
  __shared__ __align__(16) unsigned short Whs[2][O * 64];
  __shared__ __align__(16) float F2d[2][64];
  __shared__ unsigned long long Bw2[2][64];
  __shared__ float F1s[64];
  if (tid < 64) {
    int n = n0 + tid;
    F1s[tid] = (n < NNODE) ? f1[(size_t)z * NNODE + n] : 0.f;
  }
  short8v onesf;
  {
    short ov = (li == 0) ? (short)0x3F80 : (short)0;
#pragma unroll
    for (int e = 0; e < 8; ++e) onesf[e] = ov;
  }
  auto stage = [&](int t, int buf) {
    if (tid < 64) {
      int n = n0 + tid;
      Bw2[buf][tid] = (n < NNODE) ? bmA[(size_t)n * NCHUNK + kc0 + t] : 0ULL;
    } else if (tid < 128) {
      int m = (kc0 + t) * 64 + (tid - 64);
      F2d[buf][tid - 64] = (m < NNODE) ? f2B[m] : 0.f;
    }
    for (int i = tid; i < O * 8; i += 256) {
      int ro = i >> 3, c8 = i & 7;
      uint4 v = *reinterpret_cast<const uint4*>(
          WT + (size_t)ro * LDT + (size_t)(kc0 + t) * 64 + 8 * c8);
      int boff = (ro * 128 + c8 * 16) ^ ((ro & 7) << 4);
      *reinterpret_cast<uint4*>(reinterpret_cast<char*>(Whs[buf]) + boff) = v;
    }
  };
  float4v acc[NCT];
#pragma unroll
  for (int ct = 0; ct < NCT; ++ct) acc[ct] = {0.f, 0.f, 0.f, 0.f};
  float4v accs = {0.f, 0.f, 0.f, 0.f};
  stage(0, 0);
  __syncthreads();
  for (int t = 0; t < nch; ++t) {
    int buf = t & 1;
    if (t + 1 < nch) stage(t + 1, buf ^ 1);
    const unsigned long long bwr = Bw2[buf][r0 + li];
    const float f1v = F1s[r0 + li];
    short8v afr[2];
#pragma unroll
    for (int q = 0; q < 2; ++q) {
      int koff = 32 * q + 8 * g;
      unsigned bits = (unsigned)(bwr >> koff) & 0xffu;
      const float4 fa = *reinterpret_cast<const float4*>(&F2d[buf][koff]);
      const float4 fb = *reinterpret_cast<const float4*>(&F2d[buf][koff + 4]);
      float f2v[8] = {fa.x, fa.y, fa.z, fa.w, fb.x, fb.y, fb.z, fb.w};
#pragma unroll
      for (int e = 0; e < 8; ++e) {
        float tt = f1v + f2v[e];
        tt = fmaxf(tt, ALPHA * tt);
        tt = (bits & (1u << e)) ? tt : -1.0e30f;   // exp2(-1e30) = 0
        afr[q][e] = f2b(__builtin_amdgcn_exp2f(tt));
      }
    }
#pragma unroll
    for (int ct = 0; ct < NCT; ++ct) {
      int orow = ct * 16 + li;
#pragma unroll
      for (int q = 0; q < 2; ++q) {
        int boff = (orow * 128 + q * 64 + 16 * g) ^ ((li & 7) << 4);
        short8v bfr = *reinterpret_cast<const short8v*>(
            reinterpret_cast<const char*>(Whs[buf]) + boff);
        acc[ct] = __builtin_amdgcn_mfma_f32_16x16x32_bf16(afr[q], bfr, acc[ct], 0, 0, 0);
      }
    }
    accs = __builtin_amdgcn_mfma_f32_16x16x32_bf16(afr[0], onesf, accs, 0, 0, 0);
    accs = __builtin_amdgcn_mfma_f32_16x16x32_bf16(afr[1], onesf, accs, 0, 0, 0);
    __syncthreads();
  }
  if (PB16) {
    unsigned short* Cp = (unsigned short*)Cpart + ((size_t)ks * 8 + z) * NNODE * O;
#pragma unroll
    for (int j = 0; j < 4; ++j) {
      int n = n0 + r0 + 4 * g + j;
      if (n < NNODE) {
#pragma unroll
        for (int ct = 0; ct < NCT; ++ct)
          Cp[(size_t)n * O + ct * 16 + li] = (unsigned short)f2b(acc[ct][j]);
      }
    }
  } else {
    float* Cp = (float*)Cpart + ((size_t)ks * 8 + z) * NNODE * O;
#pragma unroll
    for (int j = 0; j < 4; ++j) {
      int n = n0 + r0 + 4 * g + j;
      if (n < NNODE) {
#pragma unroll
        for (int ct = 0; ct < NCT; ++ct)
          Cp[(size_t)n * O + ct * 16 + li] = acc[ct][j];
      }
    }
  }
  if (li == 0) {
#pragma unroll
    for (int j = 0; j < 4; ++j) {
      int n = n0 + r0 + 4 * g + j;
      if (n < NNODE) rsum[((size_t)ks * 8 + z) * NNODE + n] = accs[j];
    }
  }
}

// ---------------- PV reduce: sum partials, normalize, ELU, head-concat ----------------
template <int O, int KS, bool PB16, bool WB16>
__global__ __launch_bounds__(256)
void k_pvred(const void* __restrict__ Cpart, const float* __restrict__ rsum,
             float* __restrict__ Cf, unsigned short* __restrict__ Cb) {
  constexpr int C4 = O / 4;
  int idx = blockIdx.x * 256 + threadIdx.x;
  if (idx >= 8 * NNODE * C4) return;
  int zn = idx / C4, c4 = idx % C4;
  int z = zn / NNODE, n = zn % NNODE;
  int a = z >> 2, h = z & 3;
  float s = 0.f;
#pragma unroll
  for (int k = 0; k < KS; ++k) s += rsum[(size_t)k * 8 * NNODE + zn];
  float inv = (s > 0.f) ? 1.f / s : 0.f;
  float accv[4] = {0.f, 0.f, 0.f, 0.f};
#pragma unroll
  for (int k = 0; k < KS; ++k) {
    if (PB16) {
      short4v v = *reinterpret_cast<const short4v*>(
          (const unsigned short*)Cpart + (size_t)k * 8 * NNODE * O + (size_t)zn * O + 4 * c4);
#pragma unroll
      for (int j = 0; j < 4; ++j) accv[j] += b2f((unsigned short)v[j]);
    } else {
      float4 v = *reinterpret_cast<const float4*>(
          (const float*)Cpart + (size_t)k * 8 * NNODE * O + (size_t)zn * O + 4 * c4);
      accv[0] += v.x; accv[1] += v.y; accv[2] += v.z; accv[3] += v.w;
    }
  }
  size_t base = ((size_t)a * NNODE + n) * (4 * O) + (size_t)h * O + 4 * c4;
  if (WB16) {
    short4v w;
#pragma unroll
    for (int j = 0; j < 4; ++j) {
      float v = accv[j] * inv;
      v = v > 0.f ? v : (__expf(v) - 1.f);
      w[j] = f2b(v);
    }
    *reinterpret_cast<short4v*>(Cb + base) = w;
  } else {
    float4 w;
    float* wp = &w.x;
#pragma unroll
    for (int j = 0; j < 4; ++j) {
      float v = accv[j] * inv;
      wp[j] = v > 0.f ? v : (__expf(v) - 1.f);
    }
    *reinterpret_cast<float4*>(Cf + base) = w;
  }
}

// ---------------- generic tiled fp32 GEMM (tail layers) ----------------
template <int BM, int BN, int BK, int TM, int TN, bool BT, int ACT>
__global__ __launch_bounds__((BM / TM) * (BN / TN))
void k_gemm(const float* __restrict__ A, long long boffA, int ldA,
            const float* __restrict__ B, long long boffB,
            const float* __restrict__ bias,
            float* __restrict__ C, long long boffC, int ldC,
            int M, int N, int K) {
  constexpr int NT = (BM / TM) * (BN / TN);
  constexpr int NCG = BN / TN;
  const int z = blockIdx.z;
  A += boffA * z;
  B += boffB * z;
  C += boffC * z;
  const int m0 = blockIdx.x * BM;
  const int n0 = blockIdx.y * BN;
  __shared__ float As[BK][BM + 4];
  __shared__ float Bs[BK][BN + 4];
  const int tid = threadIdx.x;
  const int trow = tid / NCG, tcol = tid % NCG;
  float acc[TM][TN] = {};
  for (int k0 = 0; k0 < K; k0 += BK) {
    for (int i = tid; i < BM * BK; i += NT) {
      int r = i / BK, c = i % BK;
      int gm = m0 + r;
      As[c][r] = (gm < M) ? A[(size_t)gm * ldA + (k0 + c)] : 0.f;
    }
    if (!BT) {
      for (int i = tid; i < BK * BN; i += NT) {
        int r = i / BN, c = i % BN;
        Bs[r][c] = B[(size_t)(k0 + r) * N + (n0 + c)];
      }
    } else {
      for (int i = tid; i < BK * BN; i += NT) {
        int r = i % BK, c = i / BK;
        Bs[r][c] = B[(size_t)(n0 + c) * K + (k0 + r)];
      }
    }
    __syncthreads();
#pragma unroll 8
    for (int kk = 0; kk < BK; ++kk) {
      float ar[TM], br[TN];
#pragma unroll
      for (int i2 = 0; i2 < TM; ++i2) ar[i2] = As[kk][trow * TM + i2];
#pragma unroll
      for (int j = 0; j < TN; ++j) br[j] = Bs[kk][tcol * TN + j];
#pragma unroll
      for (int i2 = 0; i2 < TM; ++i2)
#pragma unroll
        for (int j = 0; j < TN; ++j)
          acc[i2][j] = fmaf(ar[i2], br[j], acc[i2][j]);
    }
    __syncthreads();
  }
#pragma unroll
  for (int i2 = 0; i2 < TM; ++i2) {
    int gm = m0 + trow * TM + i2;
    if (gm >= M) continue;
#pragma unroll
    for (int j = 0; j < TN; ++j) {
      int gn = n0 + tcol * TN + j;
      float v = acc[i2][j];
      if (bias) v += bias[gn];
      if (ACT == 1) v = v > 0.f ? v : (__expf(v) - 1.f);
      C[(size_t)gm * ldC + gn] = v;
    }
  }
}

// ---------------- log_softmax rows of 8 ----------------
__global__ __launch_bounds__(256)
void k_lsm(const float* __restrict__ out2, float* __restrict__ out) {
  int n = blockIdx.x * blockDim.x + threadIdx.x;
  if (n >= NNODE) return;
  const float* r = out2 + (size_t)n * 8;
  float mx = r[0];
#pragma unroll
  for (int j = 1; j < 8; ++j) mx = fmaxf(mx, r[j]);
  float s = 0.f;
#pragma unroll
  for (int j = 0; j < 8; ++j) s += __expf(r[j] - mx);
  float ls = __logf(s) + mx;
#pragma unroll
  for (int j = 0; j < 8; ++j) out[(size_t)n * 8 + j] = r[j] - ls;
}

// ---------------- L1 scalar ----------------
__global__ __launch_bounds__(256)
void k_l1(const float* __restrict__ wfus1, const float* __restrict__ wfus2,
          float* __restrict__ o) {
  __shared__ float red[256];
  int tid = threadIdx.x;
  float s1 = 0.f, s2 = 0.f;
  for (int i = tid; i < 64 * 128; i += 256) s1 += fabsf(wfus1[i]);
  if (tid < 128) s2 = fabsf(wfus2[tid]);
  red[tid] = s1 / 8192.f + s2 / 128.f;
  __syncthreads();
  for (int off = 128; off; off >>= 1) {
    if (tid < off) red[tid] += red[tid + off];
    __syncthreads();
  }
  if (tid == 0) o[0] = red[0];
}

extern "C" void kernel_launch(void* const* d_in, const int* in_sizes, int n_in,
                              void* d_out, int out_size, void* d_ws, size_t ws_size,
                              hipStream_t stream) {
  const float* x = (const float*)d_in[0];
  const int* adj = (const int*)d_in[1];
  const float* W1 = (const float*)d_in[2];
  const float* a1 = (const float*)d_in[3];
  const float* W2 = (const float*)d_in[4];
  const float* a2 = (const float*)d_in[5];
  const float* wint1 = (const float*)d_in[6];
  const float* bint1 = (const float*)d_in[7];
  const float* wfus1 = (const float*)d_in[8];
  const float* bfus1 = (const float*)d_in[9];
  const float* wint2 = (const float*)d_in[10];
  const float* bint2 = (const float*)d_in[11];
  const float* wfus2 = (const float*)d_in[12];
  const float* bfus2 = (const float*)d_in[13];
  float* out = (float*)d_out;

  // workspace layout (float offsets); peak 5,541,600 floats = 22.2 MB
  float* W = (float*)d_ws;
  unsigned long long* bm = (unsigned long long*)d_ws;          // [2][3000][47] = 0..564000
  unsigned short* xb = (unsigned short*)(W + 564000);          // [3000][512] bf16, dead after xw1
  unsigned short* h1catb = (unsigned short*)(W + 564000);      // [2][3000][256] bf16 (after reduce1)
  float* h2cat = W + 564000;                                   // [2][3000][128] f32 (after reduce2)
  unsigned short* W1Tb = (unsigned short*)(W + 1332000);       // [8][64][512] bf16
  unsigned short* wint1b = (unsigned short*)(W + 1463072);     // [64][256] bf16
  unsigned short* wfus1b = (unsigned short*)(W + 1471264);     // [64][128] bf16
  unsigned short* W2Tb = (unsigned short*)(W + 1475360);       // [8][32][64] bf16
  float* f1b = W + 1483552;                                    // [8][3000]
  float* f2g = W + 1507552;                                    // [8][3000]
  unsigned short* WhT1 = (unsigned short*)(W + 1531552);       // [8][64][3008] bf16, dead after pvp1
  unsigned short* t1b = (unsigned short*)(W + 1531552);        // [3000][128] bf16 (after int1)
  unsigned short* out1b = (unsigned short*)(W + 1723552);      // [3000][64] bf16
  unsigned short* WhT2 = (unsigned short*)(W + 1819552);       // [8][32][3008] bf16
  float* t2 = W + 2301600;                                     // [3000][16]
  float* out2 = W + 2349600;                                   // [3000][8]
  float* rsumw = W + 2373600;                                  // [4][8][3000]
  void* Cpart = (void*)(W + 2469600);                          // bf16 [4][8][3000][64] / f32 [4][8][3000][32]

  // adj -> bitmask (byte-packed, 2.256M threads)
  k_bitmask<<<dim3((2 * NNODE * NBPR + 255) / 256), 256, 0, stream>>>(
      adj, (unsigned char*)bm);
  // casts / weight transposes
  k_cast<<<dim3(750), 256, 0, stream>>>(x, xb, 192000);
  k_wt<64><<<dim3(8, 8), 256, 0, stream>>>(W1, W1Tb, 512, 512);
  k_cast<<<dim3(8), 256, 0, stream>>>(wint1, wint1b, 2048);
  k_cast<<<dim3(4), 256, 0, stream>>>(wfus1, wfus1b, 1024);
  k_wt<32><<<dim3(1, 8), 256, 0, stream>>>(W2, W2Tb, 64, 64);

  // stage 1: Wh1 + f1/f2 (pre-scaled) + WhT1, fused
  k_xw<64, 512, 1, 0><<<dim3(94, 1, 8), 128, 0, stream>>>(
      xb, 0, W1Tb, 64 * 512, a1, WhT1, (long long)64 * LDT, f1b, f2g, 0, 0);
  // PV stage 1 (K-split 4, bf16 partials) -> h1catb bf16
  k_pvp<64, 12, true><<<dim3(47, 4, 8), 256, 0, stream>>>(WhT1, f1b, f2g, bm, Cpart, rsumw);
  k_pvred<64, 4, true, true><<<dim3(1500), 256, 0, stream>>>(Cpart, rsumw, nullptr, h1catb);
  // int1 -> t1b bf16
  k_xw<32, 256, 0, 1><<<dim3(94, 2, 2), 128, 0, stream>>>(
      h1catb, (long long)NNODE * 256, wint1b, 0, bint1, t1b, 0, nullptr, nullptr, 64, 128);
  // fus1 -> out1b bf16
  k_xw<32, 128, 0, 0><<<dim3(94, 2, 1), 128, 0, stream>>>(
      t1b, 0, wfus1b, 0, bfus1, out1b, 0, nullptr, nullptr, 0, 64);

  // stage 2: Wh2 + f1/f2 (pre-scaled) + WhT2, fused
  k_xw<32, 64, 1, 0><<<dim3(94, 1, 8), 128, 0, stream>>>(
      out1b, 0, W2Tb, 32 * 64, a2, WhT2, (long long)32 * LDT, f1b, f2g, 0, 0);
  // PV stage 2 (K-split 4, fp32 partials) -> h2cat fp32
  k_pvp<32, 12, false><<<dim3(47, 4, 8), 256, 0, stream>>>(WhT2, f1b, f2g, bm, Cpart, rsumw);
  k_pvred<32, 4, false, false><<<dim3(750), 256, 0, stream>>>(Cpart, rsumw, h2cat, nullptr);

  // int2 / fus2 (fp32 tail)
  k_gemm<32, 8, 32, 2, 1, true, 1><<<dim3(94, 1, 2), 128, 0, stream>>>(
      h2cat, (long long)NNODE * 128, 128, wint2, 0, bint2, t2, 8, 16, NNODE, 8, 128);
  k_gemm<32, 8, 16, 2, 1, true, 0><<<dim3(94, 1, 1), 128, 0, stream>>>(
      t2, 0, 16, wfus2, 0, bfus2, out2, 0, 8, NNODE, 8, 16);

  // log_softmax + L1
  k_lsm<<<dim3((NNODE + 255) / 256), 256, 0, stream>>>(out2, out);
  k_l1<<<dim3(1), 256, 0, stream>>>(wfus1, wfus2, out + 24000);
}

// Round 10
// 136.569 us; speedup vs baseline: 1.5355x; 1.2006x over previous
//
#include <hip/hip_runtime.h>
#include <hip/hip_bf16.h>
#include <math.h>

#define NNODE 3000
#define NCHUNK 47  // ceil(3000/64)
#define NBPR 376   // bytes per bitmask row (47*8)
#define ALPHA 0.2f
#define LDT 3008   // padded m-stride of WhT (bf16)
#define LOG2E 1.4426950408889634f

typedef __attribute__((ext_vector_type(8))) short short8v;
typedef __attribute__((ext_vector_type(4))) short short4v;
typedef __attribute__((ext_vector_type(4))) float float4v;

static __device__ __forceinline__ short f2b(float x) {
  __hip_bfloat16 b = __float2bfloat16(x);
  return *reinterpret_cast<short*>(&b);
}
static __device__ __forceinline__ float b2f(unsigned short u) {
  unsigned v = ((unsigned)u) << 16;
  return *reinterpret_cast<float*>(&v);
}

// ---------------- fused preprocessing: one launch, concurrent regions ----------------
// blocks [0,8813): adj->bitmask bytes; [8813,9563): x cast; [9563,9627): W1T;
// [9627,9635): wint1 cast; [9635,9639): wfus1 cast; [9639,9647): W2T.
#define PB_BM 8813
#define PB_XC 750
#define PB_W1 64
#define PB_WI 8
#define PB_WF 4
#define PB_W2 8
#define PREP_BLOCKS (PB_BM + PB_XC + PB_W1 + PB_WI + PB_WF + PB_W2)

static __device__ __forceinline__ void cast8(const float* __restrict__ src,
                                             unsigned short* __restrict__ dst, int i) {
  float4 va = reinterpret_cast<const float4*>(src)[2 * i];
  float4 vb = reinterpret_cast<const float4*>(src)[2 * i + 1];
  short8v w;
  w[0] = f2b(va.x); w[1] = f2b(va.y); w[2] = f2b(va.z); w[3] = f2b(va.w);
  w[4] = f2b(vb.x); w[5] = f2b(vb.y); w[6] = f2b(vb.z); w[7] = f2b(vb.w);
  reinterpret_cast<short8v*>(dst)[i] = w;
}

static __device__ void wt_body(const float* __restrict__ src,
                               unsigned short* __restrict__ dst,
                               int rows, int O, int ldT, int m0, float* Lw) {
  const int tid = threadIdx.x;
  const int ocnt = O / 4;
  for (int idx = tid; idx < 64 * ocnt; idx += 256) {
    int m = idx / ocnt, oc = idx % ocnt;
    float4 v = make_float4(0.f, 0.f, 0.f, 0.f);
    if (m0 + m < rows)
      v = *reinterpret_cast<const float4*>(&src[(size_t)(m0 + m) * O + 4 * oc]);
    *reinterpret_cast<float4*>(&Lw[m * 68 + 4 * oc]) = v;
  }
  __syncthreads();
  const int o = tid & (O - 1);
  for (int mc = tid / O; mc < 8; mc += 256 / O) {
    short8v w;
#pragma unroll
    for (int j = 0; j < 8; ++j) w[j] = f2b(Lw[(8 * mc + j) * 68 + o]);
    *reinterpret_cast<short8v*>(&dst[(size_t)o * ldT + m0 + 8 * mc]) = w;
  }
}

__global__ __launch_bounds__(256)
void k_prep(const int* __restrict__ adj, unsigned char* __restrict__ bmb,
            const float* __restrict__ x, unsigned short* __restrict__ xb,
            const float* __restrict__ W1, unsigned short* __restrict__ W1Tb,
            const float* __restrict__ wint1, unsigned short* __restrict__ wint1b,
            const float* __restrict__ wfus1, unsigned short* __restrict__ wfus1b,
            const float* __restrict__ W2, unsigned short* __restrict__ W2Tb) {
  __shared__ float Lw[64 * 68];
  const int b = blockIdx.x;
  const int tid = threadIdx.x;
  if (b < PB_BM) {
    int idx = b * 256 + tid;
    if (idx < 2 * NNODE * NBPR) {
      int row = idx / NBPR, by = idx % NBPR;
      unsigned char v = 0;
      if (by < 375) {
        const int* p = adj + (size_t)row * NNODE + 8 * by;
        int4 a0 = *reinterpret_cast<const int4*>(p);
        int4 a1 = *reinterpret_cast<const int4*>(p + 4);
        v = (unsigned char)((a0.x > 0) | ((a0.y > 0) << 1) | ((a0.z > 0) << 2) |
                            ((a0.w > 0) << 3) | ((a1.x > 0) << 4) | ((a1.y > 0) << 5) |
                            ((a1.z > 0) << 6) | ((a1.w > 0) << 7));
      }
      bmb[idx] = v;
    }
  } else if (b < PB_BM + PB_XC) {
    int i = (b - PB_BM) * 256 + tid;
    if (i < 192000) cast8(x, xb, i);
  } else if (b < PB_BM + PB_XC + PB_W1) {
    int zb = b - (PB_BM + PB_XC);
    int z = zb >> 3, m0 = (zb & 7) * 64;
    wt_body(W1 + (size_t)z * 512 * 64, W1Tb + (size_t)z * 64 * 512, 512, 64, 512, m0, Lw);
  } else if (b < PB_BM + PB_XC + PB_W1 + PB_WI) {
    int i = (b - (PB_BM + PB_XC + PB_W1)) * 256 + tid;
    if (i < 2048) cast8(wint1, wint1b, i);
  } else if (b < PB_BM + PB_XC + PB_W1 + PB_WI + PB_WF) {
    int i = (b - (PB_BM + PB_XC + PB_W1 + PB_WI)) * 256 + tid;
    if (i < 1024) cast8(wfus1, wfus1b, i);
  } else {
    int z = b - (PB_BM + PB_XC + PB_W1 + PB_WI + PB_WF);
    wt_body(W2 + (size_t)z * 64 * 32, W2Tb + (size_t)z * 32 * 64, 64, 32, 64, 0, Lw);
  }
}

// ---------------- bf16 MFMA GEMM, 32 rows x OW cols per 128-thr block ----------------
template <int OW, int KC, int MODE, int ACT>
__global__ __launch_bounds__(128)
void k_xw(const unsigned short* __restrict__ Ab, long long boffA,
          const unsigned short* __restrict__ Bb, long long boffB,
          const float* __restrict__ aux,
          unsigned short* __restrict__ Wo,
          long long boffW,
          float* __restrict__ f1o, float* __restrict__ f2o,
          int colStrideZ, int ldC) {
  constexpr int NCT = OW / 16;
  const int z = blockIdx.z;
  const int n0 = blockIdx.x * 32;
  const int ocol0 = blockIdx.y * OW;
  const unsigned short* A = Ab + boffA * z;
  const unsigned short* B = Bb + boffB * z;
  const int tid = threadIdx.x;
  const int l = tid & 63, g = l >> 4, li = l & 15;
  const int r0 = 16 * (tid >> 6);
  __shared__ __align__(16) unsigned short As[32 * 64];
  __shared__ __align__(16) unsigned short Bs[OW * 64];
  float4v acc[NCT];
#pragma unroll
  for (int ct = 0; ct < NCT; ++ct) acc[ct] = {0.f, 0.f, 0.f, 0.f};
  for (int k0 = 0; k0 < KC; k0 += 64) {
    for (int i = tid; i < 256; i += 128) {
      int r = i >> 3, c8 = i & 7;
      uint4 v = {0u, 0u, 0u, 0u};
      if (n0 + r < NNODE)
        v = *reinterpret_cast<const uint4*>(A + (size_t)(n0 + r) * KC + k0 + 8 * c8);
      int boff = (r * 128 + c8 * 16) ^ ((r & 7) << 4);
      *reinterpret_cast<uint4*>(reinterpret_cast<char*>(As) + boff) = v;
    }
    for (int i = tid; i < OW * 8; i += 128) {
      int ro = i >> 3, c8 = i & 7;
      uint4 v = *reinterpret_cast<const uint4*>(B + (size_t)(ocol0 + ro) * KC + k0 + 8 * c8);
      int boff = (ro * 128 + c8 * 16) ^ ((ro & 7) << 4);
      *reinterpret_cast<uint4*>(reinterpret_cast<char*>(Bs) + boff) = v;
    }
    __syncthreads();
#pragma unroll
    for (int q = 0; q < 2; ++q) {
      int aoff = ((r0 + li) * 128 + q * 64 + 16 * g) ^ ((li & 7) << 4);
      short8v afr = *reinterpret_cast<const short8v*>(
          reinterpret_cast<const char*>(As) + aoff);
#pragma unroll
      for (int ct = 0; ct < NCT; ++ct) {
        int orow = ct * 16 + li;
        int boff = (orow * 128 + q * 64 + 16 * g) ^ ((li & 7) << 4);
        short8v bfr = *reinterpret_cast<const short8v*>(
            reinterpret_cast<const char*>(Bs) + boff);
        acc[ct] = __builtin_amdgcn_mfma_f32_16x16x32_bf16(afr, bfr, acc[ct], 0, 0, 0);
      }
    }
    __syncthreads();
  }
  if (MODE == 1) {
    const float* av = aux + (size_t)z * 2 * OW;
    float p1[4] = {0.f, 0.f, 0.f, 0.f}, p2[4] = {0.f, 0.f, 0.f, 0.f};
#pragma unroll
    for (int ct = 0; ct < NCT; ++ct) {
      float a1v = av[ct * 16 + li];
      float a2v = av[OW + ct * 16 + li];
#pragma unroll
      for (int j = 0; j < 4; ++j) {
        p1[j] += acc[ct][j] * a1v;
        p2[j] += acc[ct][j] * a2v;
      }
    }
#pragma unroll
    for (int off = 1; off < 16; off <<= 1) {
#pragma unroll
      for (int j = 0; j < 4; ++j) {
        p1[j] += __shfl_xor(p1[j], off);
        p2[j] += __shfl_xor(p2[j], off);
      }
    }
    unsigned short* WT = Wo + boffW * z;
#pragma unroll
    for (int ct = 0; ct < NCT; ++ct) {
      short4v w;
#pragma unroll
      for (int j = 0; j < 4; ++j) w[j] = f2b(acc[ct][j]);
      *reinterpret_cast<short4v*>(
          &WT[(size_t)(ocol0 + ct * 16 + li) * LDT + n0 + r0 + 4 * g]) = w;
    }
    if (li == 0) {
#pragma unroll
      for (int j = 0; j < 4; ++j) {
        int n = n0 + r0 + 4 * g + j;
        if (n < NNODE) {
          f1o[(size_t)z * NNODE + n] = p1[j] * LOG2E;
          f2o[(size_t)z * NNODE + n] = p2[j] * LOG2E;
        }
      }
    }
  } else {
#pragma unroll
    for (int ct = 0; ct < NCT; ++ct) {
      float b = aux[ocol0 + ct * 16 + li];
#pragma unroll
      for (int j = 0; j < 4; ++j) {
        int n = n0 + r0 + 4 * g + j;
        if (n < NNODE) {
          float v = acc[ct][j] + b;
          if (ACT == 1) v = v > 0.f ? v : (__expf(v) - 1.f);
          Wo[(size_t)n * ldC + z * colStrideZ + ocol0 + ct * 16 + li] = (unsigned short)f2b(v);
        }
      }
    }
  }
}

// ---------------- MFMA PV, K-split partials: 64 rows, 256 thr, 4 waves ----------------
template <int O, int CPS, bool PB16>
__global__ __launch_bounds__(256)
void k_pvp(const unsigned short* __restrict__ WhT,
           const float* __restrict__ f1, const float* __restrict__ f2,
           const unsigned long long* __restrict__ bm,
           void* __restrict__ Cpart, float* __restrict__ rsum) {
  constexpr int NCT = O / 16;
  const int z = blockIdx.z, a = z >> 2;
  const int ks = blockIdx.y;
  const int n0 = blockIdx.x * 64;
  const int kc0 = ks * CPS;
  const int nch = (NCHUNK - kc0 < CPS) ? (NCHUNK - kc0) : CPS;
  const int tid = threadIdx.x;
  const int l = tid & 63, li = l & 15, g = l >> 4;
  const int r0 = 16 * (tid >> 6);  // 0,16,32,48 (4 waves)
  const unsigned short* WT = WhT + (size_t)z * O * LDT;
  const float* f2B = f2 + (size_t)z * NNODE;
  const unsigned long long* bmA = bm + (size_t)a * NNODE * NCHUNK;
  __shared__ __align__(16) unsigned short Whs[2][O * 64];
  __shared__ __align__(16) float F2d[2][64];
  __shared__ unsigned long long Bw2[2][64];
  __shared__ float F1s[64];
  if (tid < 64) {
    int n = n0 + tid;
    F1s[tid] = (n < NNODE) ? f1[(size_t)z * NNODE + n] : 0.f;
  }
  short8v onesf;
  {
    short ov = (li == 0) ? (short)0x3F80 : (short)0;
#pragma unroll
    for (int e = 0; e < 8; ++e) onesf[e] = ov;
  }
  auto stage = [&](int t, int buf) {
    if (tid < 64) {
      int n = n0 + tid;
      Bw2[buf][tid] = (n < NNODE) ? bmA[(size_t)n * NCHUNK + kc0 + t] : 0ULL;
    } else if (tid < 128) {
      int m = (kc0 + t) * 64 + (tid - 64);
      F2d[buf][tid - 64] = (m < NNODE) ? f2B[m] : 0.f;
    }
    for (int i = tid; i < O * 8; i += 256) {
      int ro = i >> 3, c8 = i & 7;
      uint4 v = *reinterpret_cast<const uint4*>(
          WT + (size_t)ro * LDT + (size_t)(kc0 + t) * 64 + 8 * c8);
      int boff = (ro * 128 + c8 * 16) ^ ((ro & 7) << 4);
      *reinterpret_cast<uint4*>(reinterpret_cast<char*>(Whs[buf]) + boff) = v;
    }
  };
  float4v acc[NCT];
#pragma unroll
  for (int ct = 0; ct < NCT; ++ct) acc[ct] = {0.f, 0.f, 0.f, 0.f};
  float4v accs = {0.f, 0.f, 0.f, 0.f};
  stage(0, 0);
  __syncthreads();
  for (int t = 0; t < nch; ++t) {
    int buf = t & 1;
    if (t + 1 < nch) stage(t + 1, buf ^ 1);
    const unsigned long long bwr = Bw2[buf][r0 + li];
    const float f1v = F1s[r0 + li];
    short8v afr[2];
#pragma unroll
    for (int q = 0; q < 2; ++q) {
      int koff = 32 * q + 8 * g;
      unsigned bits = (unsigned)(bwr >> koff) & 0xffu;
      const float4 fa = *reinterpret_cast<const float4*>(&F2d[buf][koff]);
      const float4 fb = *reinterpret_cast<const float4*>(&F2d[buf][koff + 4]);
      float f2v[8] = {fa.x, fa.y, fa.z, fa.w, fb.x, fb.y, fb.z, fb.w};
#pragma unroll
      for (int e = 0; e < 8; ++e) {
        float tt = f1v + f2v[e];
        tt = fmaxf(tt, ALPHA * tt);
        tt = (bits & (1u << e)) ? tt : -1.0e30f;   // exp2(-1e30) = 0
        afr[q][e] = f2b(__builtin_amdgcn_exp2f(tt));
      }
    }
#pragma unroll
    for (int ct = 0; ct < NCT; ++ct) {
      int orow = ct * 16 + li;
#pragma unroll
      for (int q = 0; q < 2; ++q) {
        int boff = (orow * 128 + q * 64 + 16 * g) ^ ((li & 7) << 4);
        short8v bfr = *reinterpret_cast<const short8v*>(
            reinterpret_cast<const char*>(Whs[buf]) + boff);
        acc[ct] = __builtin_amdgcn_mfma_f32_16x16x32_bf16(afr[q], bfr, acc[ct], 0, 0, 0);
      }
    }
    accs = __builtin_amdgcn_mfma_f32_16x16x32_bf16(afr[0], onesf, accs, 0, 0, 0);
    accs = __builtin_amdgcn_mfma_f32_16x16x32_bf16(afr[1], onesf, accs, 0, 0, 0);
    __syncthreads();
  }
  if (PB16) {
    unsigned short* Cp = (unsigned short*)Cpart + ((size_t)ks * 8 + z) * NNODE * O;
#pragma unroll
    for (int j = 0; j < 4; ++j) {
      int n = n0 + r0 + 4 * g + j;
      if (n < NNODE) {
#pragma unroll
        for (int ct = 0; ct < NCT; ++ct)
          Cp[(size_t)n * O + ct * 16 + li] = (unsigned short)f2b(acc[ct][j]);
      }
    }
  } else {
    float* Cp = (float*)Cpart + ((size_t)ks * 8 + z) * NNODE * O;
#pragma unroll
    for (int j = 0; j < 4; ++j) {
      int n = n0 + r0 + 4 * g + j;
      if (n < NNODE) {
#pragma unroll
        for (int ct = 0; ct < NCT; ++ct)
          Cp[(size_t)n * O + ct * 16 + li] = acc[ct][j];
      }
    }
  }
  if (li == 0) {
#pragma unroll
    for (int j = 0; j < 4; ++j) {
      int n = n0 + r0 + 4 * g + j;
      if (n < NNODE) rsum[((size_t)ks * 8 + z) * NNODE + n] = accs[j];
    }
  }
}

// ---------------- PV reduce: sum partials, normalize, ELU, head-concat ----------------
template <int O, int KS, bool PB16, bool WB16>
__global__ __launch_bounds__(256)
void k_pvred(const void* __restrict__ Cpart, const float* __restrict__ rsum,
             float* __restrict__ Cf, unsigned short* __restrict__ Cb) {
  constexpr int C4 = O / 4;
  int idx = blockIdx.x * 256 + threadIdx.x;
  if (idx >= 8 * NNODE * C4) return;
  int zn = idx / C4, c4 = idx % C4;
  int z = zn / NNODE, n = zn % NNODE;
  int a = z >> 2, h = z & 3;
  float s = 0.f;
#pragma unroll
  for (int k = 0; k < KS; ++k) s += rsum[(size_t)k * 8 * NNODE + zn];
  float inv = (s > 0.f) ? 1.f / s : 0.f;
  float accv[4] = {0.f, 0.f, 0.f, 0.f};
#pragma unroll
  for (int k = 0; k < KS; ++k) {
    if (PB16) {
      short4v v = *reinterpret_cast<const short4v*>(
          (const unsigned short*)Cpart + (size_t)k * 8 * NNODE * O + (size_t)zn * O + 4 * c4);
#pragma unroll
      for (int j = 0; j < 4; ++j) accv[j] += b2f((unsigned short)v[j]);
    } else {
      float4 v = *reinterpret_cast<const float4*>(
          (const float*)Cpart + (size_t)k * 8 * NNODE * O + (size_t)zn * O + 4 * c4);
      accv[0] += v.x; accv[1] += v.y; accv[2] += v.z; accv[3] += v.w;
    }
  }
  size_t base = ((size_t)a * NNODE + n) * (4 * O) + (size_t)h * O + 4 * c4;
  if (WB16) {
    short4v w;
#pragma unroll
    for (int j = 0; j < 4; ++j) {
      float v = accv[j] * inv;
      v = v > 0.f ? v : (__expf(v) - 1.f);
      w[j] = f2b(v);
    }
    *reinterpret_cast<short4v*>(Cb + base) = w;
  } else {
    float4 w;
    float* wp = &w.x;
#pragma unroll
    for (int j = 0; j < 4; ++j) {
      float v = accv[j] * inv;
      wp[j] = v > 0.f ? v : (__expf(v) - 1.f);
    }
    *reinterpret_cast<float4*>(Cf + base) = w;
  }
}

// ---------------- fused tail: int2 + fus2 + log_softmax (+ L1 in last block) ----------
// blocks [0,750): 4 nodes each (1 wave/node). block 750: L1 scalar.
__global__ __launch_bounds__(256)
void k_tail(const float* __restrict__ h2cat, const float* __restrict__ wint2,
            const float* __restrict__ bint2, const float* __restrict__ wfus2,
            const float* __restrict__ bfus2, const float* __restrict__ wfus1,
            float* __restrict__ out) {
  const int tid = threadIdx.x;
  if (blockIdx.x == 750) {
    // L1 scalar
    __shared__ float red[256];
    float s1 = 0.f, s2 = 0.f;
    for (int i = tid; i < 64 * 128; i += 256) s1 += fabsf(wfus1[i]);
    if (tid < 128) s2 = fabsf(wfus2[tid]);
    red[tid] = s1 / 8192.f + s2 / 128.f;
    __syncthreads();
    for (int off = 128; off; off >>= 1) {
      if (tid < off) red[tid] += red[tid + off];
      __syncthreads();
    }
    if (tid == 0) out[24000] = red[0];
    return;
  }
  __shared__ float T2s[4][16];
  const int w = tid >> 6, l = tid & 63;
  const int n = blockIdx.x * 4 + w;
  const int o = l & 15, q = l >> 4;     // t2 output index, k-quarter
  const int zz = o >> 3, c = o & 7;
  // int2: t2[o] = elu( sum_k h2cat[zz][n][k] * wint2[c][k] + bint2[c] )
  const float* ar = h2cat + (size_t)zz * NNODE * 128 + (size_t)n * 128 + q * 32;
  const float* wr = wint2 + (size_t)c * 128 + q * 32;
  float s = 0.f;
#pragma unroll
  for (int i = 0; i < 8; ++i) {
    float4 av = *reinterpret_cast<const float4*>(ar + 4 * i);
    float4 wv = *reinterpret_cast<const float4*>(wr + 4 * i);
    s = fmaf(av.x, wv.x, s); s = fmaf(av.y, wv.y, s);
    s = fmaf(av.z, wv.z, s); s = fmaf(av.w, wv.w, s);
  }
  s += __shfl_xor(s, 16);
  s += __shfl_xor(s, 32);
  if (q == 0) {
    float v = s + bint2[c];
    v = v > 0.f ? v : (__expf(v) - 1.f);
    T2s[w][o] = v;
  }
  // same-wave LDS read (no barrier needed)
  if (l < 8) {
    float v = bfus2[l];
#pragma unroll
    for (int k = 0; k < 16; ++k) v = fmaf(T2s[w][k], wfus2[l * 16 + k], v);
    float mx = v;
    mx = fmaxf(mx, __shfl_xor(mx, 1, 8));
    mx = fmaxf(mx, __shfl_xor(mx, 2, 8));
    mx = fmaxf(mx, __shfl_xor(mx, 4, 8));
    float ex = __expf(v - mx);
    float sm = ex;
    sm += __shfl_xor(sm, 1, 8);
    sm += __shfl_xor(sm, 2, 8);
    sm += __shfl_xor(sm, 4, 8);
    float ls = __logf(sm) + mx;
    out[(size_t)n * 8 + l] = v - ls;
  }
}

extern "C" void kernel_launch(void* const* d_in, const int* in_sizes, int n_in,
                              void* d_out, int out_size, void* d_ws, size_t ws_size,
                              hipStream_t stream) {
  const float* x = (const float*)d_in[0];
  const int* adj = (const int*)d_in[1];
  const float* W1 = (const float*)d_in[2];
  const float* a1 = (const float*)d_in[3];
  const float* W2 = (const float*)d_in[4];
  const float* a2 = (const float*)d_in[5];
  const float* wint1 = (const float*)d_in[6];
  const float* bint1 = (const float*)d_in[7];
  const float* wfus1 = (const float*)d_in[8];
  const float* bfus1 = (const float*)d_in[9];
  const float* wint2 = (const float*)d_in[10];
  const float* bint2 = (const float*)d_in[11];
  const float* wfus2 = (const float*)d_in[12];
  const float* bfus2 = (const float*)d_in[13];
  float* out = (float*)d_out;

  // workspace layout (float offsets); peak 5,541,600 floats = 22.2 MB
  float* W = (float*)d_ws;
  unsigned long long* bm = (unsigned long long*)d_ws;          // [2][3000][47] = 0..564000
  unsigned short* xb = (unsigned short*)(W + 564000);          // [3000][512] bf16, dead after xw1
  unsigned short* h1catb = (unsigned short*)(W + 564000);      // [2][3000][256] bf16 (after reduce1)
  float* h2cat = W + 564000;                                   // [2][3000][128] f32 (after reduce2)
  unsigned short* W1Tb = (unsigned short*)(W + 1332000);       // [8][64][512] bf16
  unsigned short* wint1b = (unsigned short*)(W + 1463072);     // [64][256] bf16
  unsigned short* wfus1b = (unsigned short*)(W + 1471264);     // [64][128] bf16
  unsigned short* W2Tb = (unsigned short*)(W + 1475360);       // [8][32][64] bf16
  float* f1b = W + 1483552;                                    // [8][3000]
  float* f2g = W + 1507552;                                    // [8][3000]
  unsigned short* WhT1 = (unsigned short*)(W + 1531552);       // [8][64][3008] bf16, dead after pvp1
  unsigned short* t1b = (unsigned short*)(W + 1531552);        // [3000][128] bf16 (after int1)
  unsigned short* out1b = (unsigned short*)(W + 1723552);      // [3000][64] bf16
  unsigned short* WhT2 = (unsigned short*)(W + 1819552);       // [8][32][3008] bf16
  float* rsumw = W + 2373600;                                  // [4][8][3000]
  void* Cpart = (void*)(W + 2469600);                          // bf16 [4][8][3000][64] / f32 [4][8][3000][32]

  // fused preprocessing (bitmask + casts + weight transposes), one launch
  k_prep<<<dim3(PREP_BLOCKS), 256, 0, stream>>>(
      adj, (unsigned char*)bm, x, xb, W1, W1Tb, wint1, wint1b, wfus1, wfus1b, W2, W2Tb);

  // stage 1: Wh1 + f1/f2 (pre-scaled) + WhT1, fused
  k_xw<64, 512, 1, 0><<<dim3(94, 1, 8), 128, 0, stream>>>(
      xb, 0, W1Tb, 64 * 512, a1, WhT1, (long long)64 * LDT, f1b, f2g, 0, 0);
  // PV stage 1 (K-split 4, bf16 partials) -> h1catb bf16
  k_pvp<64, 12, true><<<dim3(47, 4, 8), 256, 0, stream>>>(WhT1, f1b, f2g, bm, Cpart, rsumw);
  k_pvred<64, 4, true, true><<<dim3(1500), 256, 0, stream>>>(Cpart, rsumw, nullptr, h1catb);
  // int1 -> t1b bf16
  k_xw<32, 256, 0, 1><<<dim3(94, 2, 2), 128, 0, stream>>>(
      h1catb, (long long)NNODE * 256, wint1b, 0, bint1, t1b, 0, nullptr, nullptr, 64, 128);
  // fus1 -> out1b bf16
  k_xw<32, 128, 0, 0><<<dim3(94, 2, 1), 128, 0, stream>>>(
      t1b, 0, wfus1b, 0, bfus1, out1b, 0, nullptr, nullptr, 0, 64);

  // stage 2: Wh2 + f1/f2 (pre-scaled) + WhT2, fused
  k_xw<32, 64, 1, 0><<<dim3(94, 1, 8), 128, 0, stream>>>(
      out1b, 0, W2Tb, 32 * 64, a2, WhT2, (long long)32 * LDT, f1b, f2g, 0, 0);
  // PV stage 2 (K-split 4, fp32 partials) -> h2cat fp32
  k_pvp<32, 12, false><<<dim3(47, 4, 8), 256, 0, stream>>>(WhT2, f1b, f2g, bm, Cpart, rsumw);
  k_pvred<32, 4, false, false><<<dim3(750), 256, 0, stream>>>(Cpart, rsumw, h2cat, nullptr);

  // fused tail: int2 + fus2 + log_softmax + L1
  k_tail<<<dim3(751), 256, 0, stream>>>(h2cat, wint2, bint2, wfus2, bfus2, wfus1, out);
}

// Round 11
// 135.903 us; speedup vs baseline: 1.5431x; 1.0049x over previous
//
#include <hip/hip_runtime.h>
#include <hip/hip_bf16.h>
#include <math.h>

#define NNODE 3000
#define NCHUNK 47  // ceil(3000/64)
#define NBPR 376   // bytes per bitmask row (47*8)
#define ALPHA 0.2f
#define LDT 3008   // padded m-stride of WhT (bf16)
#define LOG2E 1.4426950408889634f

typedef __attribute__((ext_vector_type(8))) short short8v;
typedef __attribute__((ext_vector_type(4))) short short4v;
typedef __attribute__((ext_vector_type(4))) float float4v;

static __device__ __forceinline__ short f2b(float x) {
  __hip_bfloat16 b = __float2bfloat16(x);
  return *reinterpret_cast<short*>(&b);
}
static __device__ __forceinline__ float b2f(unsigned short u) {
  unsigned v = ((unsigned)u) << 16;
  return *reinterpret_cast<float*>(&v);
}

// ---------------- fused preprocessing: one launch, concurrent regions ----------------
#define PB_BM 8813
#define PB_XC 750
#define PB_W1 64
#define PB_WI 8
#define PB_WF 4
#define PB_W2 8
#define PREP_BLOCKS (PB_BM + PB_XC + PB_W1 + PB_WI + PB_WF + PB_W2)

static __device__ __forceinline__ void cast8(const float* __restrict__ src,
                                             unsigned short* __restrict__ dst, int i) {
  float4 va = reinterpret_cast<const float4*>(src)[2 * i];
  float4 vb = reinterpret_cast<const float4*>(src)[2 * i + 1];
  short8v w;
  w[0] = f2b(va.x); w[1] = f2b(va.y); w[2] = f2b(va.z); w[3] = f2b(va.w);
  w[4] = f2b(vb.x); w[5] = f2b(vb.y); w[6] = f2b(vb.z); w[7] = f2b(vb.w);
  reinterpret_cast<short8v*>(dst)[i] = w;
}

static __device__ void wt_body(const float* __restrict__ src,
                               unsigned short* __restrict__ dst,
                               int rows, int O, int ldT, int m0, float* Lw) {
  const int tid = threadIdx.x;
  const int ocnt = O / 4;
  for (int idx = tid; idx < 64 * ocnt; idx += 256) {
    int m = idx / ocnt, oc = idx % ocnt;
    float4 v = make_float4(0.f, 0.f, 0.f, 0.f);
    if (m0 + m < rows)
      v = *reinterpret_cast<const float4*>(&src[(size_t)(m0 + m) * O + 4 * oc]);
    *reinterpret_cast<float4*>(&Lw[m * 68 + 4 * oc]) = v;
  }
  __syncthreads();
  const int o = tid & (O - 1);
  for (int mc = tid / O; mc < 8; mc += 256 / O) {
    short8v w;
#pragma unroll
    for (int j = 0; j < 8; ++j) w[j] = f2b(Lw[(8 * mc + j) * 68 + o]);
    *reinterpret_cast<short8v*>(&dst[(size_t)o * ldT + m0 + 8 * mc]) = w;
  }
}

__global__ __launch_bounds__(256)
void k_prep(const int* __restrict__ adj, unsigned char* __restrict__ bmb,
            const float* __restrict__ x, unsigned short* __restrict__ xb,
            const float* __restrict__ W1, unsigned short* __restrict__ W1Tb,
            const float* __restrict__ wint1, unsigned short* __restrict__ wint1b,
            const float* __restrict__ wfus1, unsigned short* __restrict__ wfus1b,
            const float* __restrict__ W2, unsigned short* __restrict__ W2Tb) {
  __shared__ float Lw[64 * 68];
  const int b = blockIdx.x;
  const int tid = threadIdx.x;
  if (b < PB_BM) {
    int idx = b * 256 + tid;
    if (idx < 2 * NNODE * NBPR) {
      int row = idx / NBPR, by = idx % NBPR;
      unsigned char v = 0;
      if (by < 375) {
        const int* p = adj + (size_t)row * NNODE + 8 * by;
        int4 a0 = *reinterpret_cast<const int4*>(p);
        int4 a1 = *reinterpret_cast<const int4*>(p + 4);
        v = (unsigned char)((a0.x > 0) | ((a0.y > 0) << 1) | ((a0.z > 0) << 2) |
                            ((a0.w > 0) << 3) | ((a1.x > 0) << 4) | ((a1.y > 0) << 5) |
                            ((a1.z > 0) << 6) | ((a1.w > 0) << 7));
      }
      bmb[idx] = v;
    }
  } else if (b < PB_BM + PB_XC) {
    int i = (b - PB_BM) * 256 + tid;
    if (i < 192000) cast8(x, xb, i);
  } else if (b < PB_BM + PB_XC + PB_W1) {
    int zb = b - (PB_BM + PB_XC);
    int z = zb >> 3, m0 = (zb & 7) * 64;
    wt_body(W1 + (size_t)z * 512 * 64, W1Tb + (size_t)z * 64 * 512, 512, 64, 512, m0, Lw);
  } else if (b < PB_BM + PB_XC + PB_W1 + PB_WI) {
    int i = (b - (PB_BM + PB_XC + PB_W1)) * 256 + tid;
    if (i < 2048) cast8(wint1, wint1b, i);
  } else if (b < PB_BM + PB_XC + PB_W1 + PB_WI + PB_WF) {
    int i = (b - (PB_BM + PB_XC + PB_W1 + PB_WI)) * 256 + tid;
    if (i < 1024) cast8(wfus1, wfus1b, i);
  } else {
    int z = b - (PB_BM + PB_XC + PB_W1 + PB_WI + PB_WF);
    wt_body(W2 + (size_t)z * 64 * 32, W2Tb + (size_t)z * 32 * 64, 64, 32, 64, 0, Lw);
  }
}

// ---------------- bf16 MFMA GEMM, 32 rows x OW cols per 128-thr block ----------------
// AF=1: A-tile generated from stage-1 PV partials (normalize+ELU+bf16 on the fly).
template <int OW, int KC, int MODE, int ACT, int AF>
__global__ __launch_bounds__(128)
void k_xw(const unsigned short* __restrict__ Ab, long long boffA,
          const unsigned short* __restrict__ Bb, long long boffB,
          const float* __restrict__ aux,
          unsigned short* __restrict__ Wo,
          long long boffW,
          float* __restrict__ f1o, float* __restrict__ f2o,
          const float* __restrict__ rs4,
          int colStrideZ, int ldC) {
  constexpr int NCT = OW / 16;
  const int z = blockIdx.z;
  const int n0 = blockIdx.x * 32;
  const int ocol0 = blockIdx.y * OW;
  const unsigned short* A = Ab + (AF ? 0 : boffA * z);
  const unsigned short* B = Bb + boffB * z;
  const int tid = threadIdx.x;
  const int l = tid & 63, g = l >> 4, li = l & 15;
  const int r0 = 16 * (tid >> 6);
  __shared__ __align__(16) unsigned short As[32 * 64];
  __shared__ __align__(16) unsigned short Bs[OW * 64];
  float4v acc[NCT];
#pragma unroll
  for (int ct = 0; ct < NCT; ++ct) acc[ct] = {0.f, 0.f, 0.f, 0.f};
  for (int k0 = 0; k0 < KC; k0 += 64) {
    for (int i = tid; i < 256; i += 128) {
      int r = i >> 3, c8 = i & 7;
      uint4 v = {0u, 0u, 0u, 0u};
      int n = n0 + r;
      if (n < NNODE) {
        if (AF) {
          // stage-1 PV partials: h = k0/64, zp = a*4+h; val = ELU((Σks p)·inv)
          int zp = z * 4 + (k0 >> 6);
          float s = rs4[(size_t)(0 * 8 + zp) * NNODE + n] +
                    rs4[(size_t)(1 * 8 + zp) * NNODE + n] +
                    rs4[(size_t)(2 * 8 + zp) * NNODE + n] +
                    rs4[(size_t)(3 * 8 + zp) * NNODE + n];
          float inv = (s > 0.f) ? 1.f / s : 0.f;
          size_t base = ((size_t)zp * NNODE + n) * 64 + 8 * c8;
          short8v p0 = *reinterpret_cast<const short8v*>(A + base);
          short8v p1 = *reinterpret_cast<const short8v*>(A + (size_t)8 * NNODE * 64 + base);
          short8v p2 = *reinterpret_cast<const short8v*>(A + (size_t)16 * NNODE * 64 + base);
          short8v p3 = *reinterpret_cast<const short8v*>(A + (size_t)24 * NNODE * 64 + base);
          short8v w;
#pragma unroll
          for (int e = 0; e < 8; ++e) {
            float sv = b2f((unsigned short)p0[e]) + b2f((unsigned short)p1[e]) +
                       b2f((unsigned short)p2[e]) + b2f((unsigned short)p3[e]);
            sv *= inv;
            sv = sv > 0.f ? sv : (__expf(sv) - 1.f);
            w[e] = f2b(sv);
          }
          v = *reinterpret_cast<uint4*>(&w);
        } else {
          v = *reinterpret_cast<const uint4*>(A + (size_t)n * KC + k0 + 8 * c8);
        }
      }
      int boff = (r * 128 + c8 * 16) ^ ((r & 7) << 4);
      *reinterpret_cast<uint4*>(reinterpret_cast<char*>(As) + boff) = v;
    }
    for (int i = tid; i < OW * 8; i += 128) {
      int ro = i >> 3, c8 = i & 7;
      uint4 v = *reinterpret_cast<const uint4*>(B + (size_t)(ocol0 + ro) * KC + k0 + 8 * c8);
      int boff = (ro * 128 + c8 * 16) ^ ((ro & 7) << 4);
      *reinterpret_cast<uint4*>(reinterpret_cast<char*>(Bs) + boff) = v;
    }
    __syncthreads();
#pragma unroll
    for (int q = 0; q < 2; ++q) {
      int aoff = ((r0 + li) * 128 + q * 64 + 16 * g) ^ ((li & 7) << 4);
      short8v afr = *reinterpret_cast<const short8v*>(
          reinterpret_cast<const char*>(As) + aoff);
#pragma unroll
      for (int ct = 0; ct < NCT; ++ct) {
        int orow = ct * 16 + li;
        int boff = (orow * 128 + q * 64 + 16 * g) ^ ((li & 7) << 4);
        short8v bfr = *reinterpret_cast<const short8v*>(
            reinterpret_cast<const char*>(Bs) + boff);
        acc[ct] = __builtin_amdgcn_mfma_f32_16x16x32_bf16(afr, bfr, acc[ct], 0, 0, 0);
      }
    }
    __syncthreads();
  }
  if (MODE == 1) {
    const float* av = aux + (size_t)z * 2 * OW;
    float p1[4] = {0.f, 0.f, 0.f, 0.f}, p2[4] = {0.f, 0.f, 0.f, 0.f};
#pragma unroll
    for (int ct = 0; ct < NCT; ++ct) {
      float a1v = av[ct * 16 + li];
      float a2v = av[OW + ct * 16 + li];
#pragma unroll
      for (int j = 0; j < 4; ++j) {
        p1[j] += acc[ct][j] * a1v;
        p2[j] += acc[ct][j] * a2v;
      }
    }
#pragma unroll
    for (int off = 1; off < 16; off <<= 1) {
#pragma unroll
      for (int j = 0; j < 4; ++j) {
        p1[j] += __shfl_xor(p1[j], off);
        p2[j] += __shfl_xor(p2[j], off);
      }
    }
    unsigned short* WT = Wo + boffW * z;
#pragma unroll
    for (int ct = 0; ct < NCT; ++ct) {
      short4v w;
#pragma unroll
      for (int j = 0; j < 4; ++j) w[j] = f2b(acc[ct][j]);
      *reinterpret_cast<short4v*>(
          &WT[(size_t)(ocol0 + ct * 16 + li) * LDT + n0 + r0 + 4 * g]) = w;
    }
    if (li == 0) {
#pragma unroll
      for (int j = 0; j < 4; ++j) {
        int n = n0 + r0 + 4 * g + j;
        if (n < NNODE) {
          f1o[(size_t)z * NNODE + n] = p1[j] * LOG2E;
          f2o[(size_t)z * NNODE + n] = p2[j] * LOG2E;
        }
      }
    }
  } else {
#pragma unroll
    for (int ct = 0; ct < NCT; ++ct) {
      float b = aux[ocol0 + ct * 16 + li];
#pragma unroll
      for (int j = 0; j < 4; ++j) {
        int n = n0 + r0 + 4 * g + j;
        if (n < NNODE) {
          float v = acc[ct][j] + b;
          if (ACT == 1) v = v > 0.f ? v : (__expf(v) - 1.f);
          Wo[(size_t)n * ldC + z * colStrideZ + ocol0 + ct * 16 + li] = (unsigned short)f2b(v);
        }
      }
    }
  }
}

// ---------------- MFMA PV, K-split partials: 64 rows, 256 thr, 4 waves ----------------
template <int O, int CPS, bool PB16>
__global__ __launch_bounds__(256)
void k_pvp(const unsigned short* __restrict__ WhT,
           const float* __restrict__ f1, const float* __restrict__ f2,
           const unsigned long long* __restrict__ bm,
           void* __restrict__ Cpart, float* __restrict__ rsum) {
  constexpr int NCT = O / 16;
  const int z = blockIdx.z, a = z >> 2;
  const int ks = blockIdx.y;
  const int n0 = blockIdx.x * 64;
  const int kc0 = ks * CPS;
  const int nch = (NCHUNK - kc0 < CPS) ? (NCHUNK - kc0) : CPS;
  const int tid = threadIdx.x;
  const int l = tid & 63, li = l & 15, g = l >> 4;
  const int r0 = 16 * (tid >> 6);  // 0,16,32,48 (4 waves)
  const unsigned short* WT = WhT + (size_t)z * O * LDT;
  const float* f2B = f2 + (size_t)z * NNODE;
  const unsigned long long* bmA = bm + (size_t)a * NNODE * NCHUNK;
  __shared__ __align__(16) unsigned short Whs[2][O * 64];
  __shared__ __align__(16) float F2d[2][64];
  __shared__ unsigned long long Bw2[2][64];
  __shared__ float F1s[64];
  if (tid < 64) {
    int n = n0 + tid;
    F1s[tid] = (n < NNODE) ? f1[(size_t)z * NNODE + n] : 0.f;
  }
  short8v onesf;
  {
    short ov = (li == 0) ? (short)0x3F80 : (short)0;
#pragma unroll
    for (int e = 0; e < 8; ++e) onesf[e] = ov;
  }
  auto stage = [&](int t, int buf) {
    if (tid < 64) {
      int n = n0 + tid;
      Bw2[buf][tid] = (n < NNODE) ? bmA[(size_t)n * NCHUNK + kc0 + t] : 0ULL;
    } else if (tid < 128) {
      int m = (kc0 + t) * 64 + (tid - 64);
      F2d[buf][tid - 64] = (m < NNODE) ? f2B[m] : 0.f;
    }
    for (int i = tid; i < O * 8; i += 256) {
      int ro = i >> 3, c8 = i & 7;
      uint4 v = *reinterpret_cast<const uint4*>(
          WT + (size_t)ro * LDT + (size_t)(kc0 + t) * 64 + 8 * c8);
      int boff = (ro * 128 + c8 * 16) ^ ((ro & 7) << 4);
      *reinterpret_cast<uint4*>(reinterpret_cast<char*>(Whs[buf]) + boff) = v;
    }
  };
  float4v acc[NCT];
#pragma unroll
  for (int ct = 0; ct < NCT; ++ct) acc[ct] = {0.f, 0.f, 0.f, 0.f};
  float4v accs = {0.f, 0.f, 0.f, 0.f};
  stage(0, 0);
  __syncthreads();
  for (int t = 0; t < nch; ++t) {
    int buf = t & 1;
    if (t + 1 < nch) stage(t + 1, buf ^ 1);
    const unsigned long long bwr = Bw2[buf][r0 + li];
    const float f1v = F1s[r0 + li];
    short8v afr[2];
#pragma unroll
    for (int q = 0; q < 2; ++q) {
      int koff = 32 * q + 8 * g;
      unsigned bits = (unsigned)(bwr >> koff) & 0xffu;
      const float4 fa = *reinterpret_cast<const float4*>(&F2d[buf][koff]);
      const float4 fb = *reinterpret_cast<const float4*>(&F2d[buf][koff + 4]);
      float f2v[8] = {fa.x, fa.y, fa.z, fa.w, fb.x, fb.y, fb.z, fb.w};
#pragma unroll
      for (int e = 0; e < 8; ++e) {
        float tt = f1v + f2v[e];
        tt = fmaxf(tt, ALPHA * tt);
        tt = (bits & (1u << e)) ? tt : -1.0e30f;   // exp2(-1e30) = 0
        afr[q][e] = f2b(__builtin_amdgcn_exp2f(tt));
      }
    }
#pragma unroll
    for (int ct = 0; ct < NCT; ++ct) {
      int orow = ct * 16 + li;
#pragma unroll
      for (int q = 0; q < 2; ++q) {
        int boff = (orow * 128 + q * 64 + 16 * g) ^ ((li & 7) << 4);
        short8v bfr = *reinterpret_cast<const short8v*>(
            reinterpret_cast<const char*>(Whs[buf]) + boff);
        acc[ct] = __builtin_amdgcn_mfma_f32_16x16x32_bf16(afr[q], bfr, acc[ct], 0, 0, 0);
      }
    }
    accs = __builtin_amdgcn_mfma_f32_16x16x32_bf16(afr[0], onesf, accs, 0, 0, 0);
    accs = __builtin_amdgcn_mfma_f32_16x16x32_bf16(afr[1], onesf, accs, 0, 0, 0);
    __syncthreads();
  }
  if (PB16) {
    unsigned short* Cp = (unsigned short*)Cpart + ((size_t)ks * 8 + z) * NNODE * O;
#pragma unroll
    for (int j = 0; j < 4; ++j) {
      int n = n0 + r0 + 4 * g + j;
      if (n < NNODE) {
#pragma unroll
        for (int ct = 0; ct < NCT; ++ct)
          Cp[(size_t)n * O + ct * 16 + li] = (unsigned short)f2b(acc[ct][j]);
      }
    }
  } else {
    float* Cp = (float*)Cpart + ((size_t)ks * 8 + z) * NNODE * O;
#pragma unroll
    for (int j = 0; j < 4; ++j) {
      int n = n0 + r0 + 4 * g + j;
      if (n < NNODE) {
#pragma unroll
        for (int ct = 0; ct < NCT; ++ct)
          Cp[(size_t)n * O + ct * 16 + li] = acc[ct][j];
      }
    }
  }
  if (li == 0) {
#pragma unroll
    for (int j = 0; j < 4; ++j) {
      int n = n0 + r0 + 4 * g + j;
      if (n < NNODE) rsum[((size_t)ks * 8 + z) * NNODE + n] = accs[j];
    }
  }
}

// ---------------- fused tail: pvred2 + int2 + fus2 + log_softmax (+ L1) ----------
// blocks [0,750): 4 nodes each (1 wave/node). block 750: L1 scalar.
__global__ __launch_bounds__(256)
void k_tail(const float* __restrict__ Cpf, const float* __restrict__ rs4,
            const float* __restrict__ wint2, const float* __restrict__ bint2,
            const float* __restrict__ wfus2, const float* __restrict__ bfus2,
            const float* __restrict__ wfus1, float* __restrict__ out) {
  const int tid = threadIdx.x;
  if (blockIdx.x == 750) {
    __shared__ float red[256];
    float s1 = 0.f, s2 = 0.f;
    for (int i = tid; i < 64 * 128; i += 256) s1 += fabsf(wfus1[i]);
    if (tid < 128) s2 = fabsf(wfus2[tid]);
    red[tid] = s1 / 8192.f + s2 / 128.f;
    __syncthreads();
    for (int off = 128; off; off >>= 1) {
      if (tid < off) red[tid] += red[tid + off];
      __syncthreads();
    }
    if (tid == 0) out[24000] = red[0];
    return;
  }
  __shared__ float T2s[4][16];
  const int w = tid >> 6, l = tid & 63;
  const int n = blockIdx.x * 4 + w;
  const int o = l & 15, q = l >> 4;     // t2 output index, k-quarter (== head h)
  const int zz = o >> 3, c = o & 7;
  const int zp = zz * 4 + q;
  // normalize factor for (zp, n)
  float s4 = rs4[(size_t)(0 * 8 + zp) * NNODE + n] +
             rs4[(size_t)(1 * 8 + zp) * NNODE + n] +
             rs4[(size_t)(2 * 8 + zp) * NNODE + n] +
             rs4[(size_t)(3 * 8 + zp) * NNODE + n];
  float inv = (s4 > 0.f) ? 1.f / s4 : 0.f;
  // int2 partial dot: k = q*32 + i, h2cat value = ELU((Σks Cp)·inv)
  const float* wr = wint2 + (size_t)c * 128 + q * 32;
  size_t base = ((size_t)zp * NNODE + n) * 32;
  const size_t pls = (size_t)8 * NNODE * 32;  // ks-plane stride
  float s = 0.f;
#pragma unroll
  for (int i = 0; i < 8; ++i) {
    float4 p0 = *reinterpret_cast<const float4*>(Cpf + base + 4 * i);
    float4 p1 = *reinterpret_cast<const float4*>(Cpf + pls + base + 4 * i);
    float4 p2 = *reinterpret_cast<const float4*>(Cpf + 2 * pls + base + 4 * i);
    float4 p3 = *reinterpret_cast<const float4*>(Cpf + 3 * pls + base + 4 * i);
    float4 wv = *reinterpret_cast<const float4*>(wr + 4 * i);
    float v0 = (p0.x + p1.x + p2.x + p3.x) * inv;
    float v1 = (p0.y + p1.y + p2.y + p3.y) * inv;
    float v2 = (p0.z + p1.z + p2.z + p3.z) * inv;
    float v3 = (p0.w + p1.w + p2.w + p3.w) * inv;
    v0 = v0 > 0.f ? v0 : (__expf(v0) - 1.f);
    v1 = v1 > 0.f ? v1 : (__expf(v1) - 1.f);
    v2 = v2 > 0.f ? v2 : (__expf(v2) - 1.f);
    v3 = v3 > 0.f ? v3 : (__expf(v3) - 1.f);
    s = fmaf(v0, wv.x, s); s = fmaf(v1, wv.y, s);
    s = fmaf(v2, wv.z, s); s = fmaf(v3, wv.w, s);
  }
  s += __shfl_xor(s, 16);
  s += __shfl_xor(s, 32);
  if (q == 0) {
    float v = s + bint2[c];
    v = v > 0.f ? v : (__expf(v) - 1.f);
    T2s[w][o] = v;
  }
  // same-wave LDS read (no barrier needed)
  if (l < 8) {
    float v = bfus2[l];
#pragma unroll
    for (int k = 0; k < 16; ++k) v = fmaf(T2s[w][k], wfus2[l * 16 + k], v);
    float mx = v;
    mx = fmaxf(mx, __shfl_xor(mx, 1, 8));
    mx = fmaxf(mx, __shfl_xor(mx, 2, 8));
    mx = fmaxf(mx, __shfl_xor(mx, 4, 8));
    float ex = __expf(v - mx);
    float sm = ex;
    sm += __shfl_xor(sm, 1, 8);
    sm += __shfl_xor(sm, 2, 8);
    sm += __shfl_xor(sm, 4, 8);
    float ls = __logf(sm) + mx;
    out[(size_t)n * 8 + l] = v - ls;
  }
}

extern "C" void kernel_launch(void* const* d_in, const int* in_sizes, int n_in,
                              void* d_out, int out_size, void* d_ws, size_t ws_size,
                              hipStream_t stream) {
  const float* x = (const float*)d_in[0];
  const int* adj = (const int*)d_in[1];
  const float* W1 = (const float*)d_in[2];
  const float* a1 = (const float*)d_in[3];
  const float* W2 = (const float*)d_in[4];
  const float* a2 = (const float*)d_in[5];
  const float* wint1 = (const float*)d_in[6];
  const float* bint1 = (const float*)d_in[7];
  const float* wfus1 = (const float*)d_in[8];
  const float* bfus1 = (const float*)d_in[9];
  const float* wint2 = (const float*)d_in[10];
  const float* bint2 = (const float*)d_in[11];
  const float* wfus2 = (const float*)d_in[12];
  const float* bfus2 = (const float*)d_in[13];
  float* out = (float*)d_out;

  // workspace layout (float offsets); peak 5,541,600 floats = 22.2 MB
  float* W = (float*)d_ws;
  unsigned long long* bm = (unsigned long long*)d_ws;          // [2][3000][47] = 0..564000
  unsigned short* xb = (unsigned short*)(W + 564000);          // [3000][512] bf16, dead after xw1
  unsigned short* W1Tb = (unsigned short*)(W + 1332000);       // [8][64][512] bf16
  unsigned short* wint1b = (unsigned short*)(W + 1463072);     // [64][256] bf16
  unsigned short* wfus1b = (unsigned short*)(W + 1471264);     // [64][128] bf16
  unsigned short* W2Tb = (unsigned short*)(W + 1475360);       // [8][32][64] bf16
  float* f1b = W + 1483552;                                    // [8][3000]
  float* f2g = W + 1507552;                                    // [8][3000]
  unsigned short* WhT1 = (unsigned short*)(W + 1531552);       // [8][64][3008] bf16, dead after pvp1
  unsigned short* t1b = (unsigned short*)(W + 1531552);        // [3000][128] bf16 (after int1)
  unsigned short* out1b = (unsigned short*)(W + 1723552);      // [3000][64] bf16
  unsigned short* WhT2 = (unsigned short*)(W + 1819552);       // [8][32][3008] bf16
  float* rsumw = W + 2373600;                                  // [4][8][3000]
  void* Cpart = (void*)(W + 2469600);                          // bf16 [4][8][3000][64] / f32 [4][8][3000][32]

  // fused preprocessing (bitmask + casts + weight transposes), one launch
  k_prep<<<dim3(PREP_BLOCKS), 256, 0, stream>>>(
      adj, (unsigned char*)bm, x, xb, W1, W1Tb, wint1, wint1b, wfus1, wfus1b, W2, W2Tb);

  // stage 1: Wh1 + f1/f2 (pre-scaled) + WhT1, fused
  k_xw<64, 512, 1, 0, 0><<<dim3(94, 1, 8), 128, 0, stream>>>(
      xb, 0, W1Tb, 64 * 512, a1, WhT1, (long long)64 * LDT, f1b, f2g, nullptr, 0, 0);
  // PV stage 1 (K-split 4, bf16 partials)
  k_pvp<64, 12, true><<<dim3(47, 4, 8), 256, 0, stream>>>(WhT1, f1b, f2g, bm, Cpart, rsumw);
  // int1 (fused pvred1 in A-path) -> t1b bf16
  k_xw<32, 256, 0, 1, 1><<<dim3(94, 2, 2), 128, 0, stream>>>(
      (const unsigned short*)Cpart, 0, wint1b, 0, bint1, t1b, 0, nullptr, nullptr,
      rsumw, 64, 128);
  // fus1 -> out1b bf16
  k_xw<32, 128, 0, 0, 0><<<dim3(94, 2, 1), 128, 0, stream>>>(
      t1b, 0, wfus1b, 0, bfus1, out1b, 0, nullptr, nullptr, nullptr, 0, 64);

  // stage 2: Wh2 + f1/f2 (pre-scaled) + WhT2, fused
  k_xw<32, 64, 1, 0, 0><<<dim3(94, 1, 8), 128, 0, stream>>>(
      out1b, 0, W2Tb, 32 * 64, a2, WhT2, (long long)32 * LDT, f1b, f2g, nullptr, 0, 0);
  // PV stage 2 (K-split 4, fp32 partials)
  k_pvp<32, 12, false><<<dim3(47, 4, 8), 256, 0, stream>>>(WhT2, f1b, f2g, bm, Cpart, rsumw);

  // fused tail: pvred2 + int2 + fus2 + log_softmax + L1
  k_tail<<<dim3(751), 256, 0, stream>>>(
      (const float*)Cpart, rsumw, wint2, bint2, wfus2, bfus2, wfus1, out);
}